// Round 6
// baseline (337.013 us; speedup 1.0000x reference)
//
#include <hip/hip_runtime.h>
#include <stdint.h>

// SelfOrganizingBrain: B=1024, IN=784, E=256, NCLS=10, N=64 blocks, NJUMPS=4.
// R5: fix VGPR-starved ILP (R1 showed VGPR_Count=32, VALUBusy 13% -> weight
// streams latency-serialized). Depth-2 register prefetch of weight quads in
// every K-loop + __launch_bounds__(1024,4) (128-VGPR cap). Structure: 10
// dispatches E+A0 -> 4x(B_j, A_{j+1}) -> B4+head; in-place state, no global
// atomics (nn_all + per-WG LDS histogram), XCD swizzle on B grids.
// FMA order identical to R2/R4 (bit-exact logits -> same gumbel argmax).

#define BATCH 1024
#define EDIM  256
#define INDIM 784
#define GRID_B 192   // max chunks = sum ceil(cnt_n/8) <= 184

// ---------------- threefry2x32 (exact JAX semantics, validated R0-R4) ----------------
__host__ __device__ inline uint32_t rotl32(uint32_t x, uint32_t d) {
  return (x << d) | (x >> (32u - d));
}
__host__ __device__ inline void threefry2x32(uint32_t k0, uint32_t k1,
                                             uint32_t x0, uint32_t x1,
                                             uint32_t* o0, uint32_t* o1) {
  uint32_t ks2 = k0 ^ k1 ^ 0x1BD11BDAu;
  x0 += k0; x1 += k1;
#define TF_R(a) { x0 += x1; x1 = rotl32(x1, a); x1 ^= x0; }
  TF_R(13) TF_R(15) TF_R(26) TF_R(6)   x0 += k1;  x1 += ks2 + 1u;
  TF_R(17) TF_R(29) TF_R(16) TF_R(24)  x0 += ks2; x1 += k0  + 2u;
  TF_R(13) TF_R(15) TF_R(26) TF_R(6)   x0 += k0;  x1 += k1  + 3u;
  TF_R(17) TF_R(29) TF_R(16) TF_R(24)  x0 += k1;  x1 += ks2 + 4u;
  TF_R(13) TF_R(15) TF_R(26) TF_R(6)   x0 += ks2; x1 += k0  + 5u;
#undef TF_R
  *o0 = x0; *o1 = x1;
}
__device__ inline uint32_t jax_bits12288(uint32_t k0, uint32_t k1, uint32_t L) {
  uint32_t o0, o1;
  if (L < 6144u) { threefry2x32(k0, k1, L, L + 6144u, &o0, &o1); return o0; }
  else           { threefry2x32(k0, k1, L - 6144u, L, &o0, &o1); return o1; }
}
__device__ inline float jax_uniform(uint32_t bits) {
  const float minv = 1e-6f;
  const float maxv = (float)(1.0 - 1e-06);
  const float span = maxv - minv;
  uint32_t fb = (bits >> 9) | 0x3f800000u;
  float f = __uint_as_float(fb) - 1.0f;
  float u = __fadd_rn(__fmul_rn(f, span), minv);
  return fmaxf(minv, u);
}
__device__ inline float gumbel_val(int s, int b, int c) {
  uint32_t fk0, fk1;
  threefry2x32(0u, 42u, 0u, (uint32_t)s, &fk0, &fk1);   // fold_in(key(42), s)
  const uint32_t L = (uint32_t)(b * 12 + c);
  const float u = jax_uniform(jax_bits12288(fk0, fk1, L));
  return -logf(-logf(u));
}
__device__ inline int addr_argmax(const float* v) {
  int i0 = 0, i1 = 0, i2 = 0;
  { float b = v[0];
    for (int c = 1; c < 4; c++) { float x = v[c];     if (x > b) { b = x; i0 = c; } } }
  { float b = v[4];
    for (int c = 1; c < 4; c++) { float x = v[4 + c]; if (x > b) { b = x; i1 = c; } } }
  { float b = v[8];
    for (int c = 1; c < 4; c++) { float x = v[8 + c]; if (x > b) { b = x; i2 = c; } } }
  return i0 * 16 + i1 * 4 + i2;
}

// load 4 consecutive-k weights of one column (stride EDIM)
__device__ __forceinline__ void ldw4(float w[4], const float* __restrict__ Wc) {
  w[0] = Wc[0]; w[1] = Wc[EDIM]; w[2] = Wc[2 * EDIM]; w[3] = Wc[3 * EDIM];
}
#define ROT_W() { _Pragma("unroll") for (int q = 0; q < 4; q++) { w0[q] = w1r[q]; w1r[q] = w2r[q]; } }

// ============ E + A0: embed 4 rows/WG + addr step 0 ============
__global__ __launch_bounds__(1024, 4) void k_embed_a0(
    const float* __restrict__ x, const float* __restrict__ Wemb,
    const float* __restrict__ bemb,
    const float* __restrict__ aW1, const float* __restrict__ ab1,
    const float* __restrict__ aW2, const float* __restrict__ ab2,
    float* __restrict__ state, float* __restrict__ initial,
    int* __restrict__ nn_all) {
  __shared__ float XS[4 * INDIM];
  __shared__ float P[4][256][5];
  __shared__ float SS[4 * EDIM];
  __shared__ float H[EDIM][4];
  __shared__ float P2[16][4][16];
  __shared__ float vals[4][12];
  const int t = threadIdx.x, b0 = blockIdx.x * 4;

  { const float4* src = (const float4*)(x + (size_t)b0 * INDIM);
    float4* dst = (float4*)XS;
    for (int p = t; p < INDIM; p += 1024) dst[p] = src[p];
  }
  __syncthreads();

  const int j = t & 255, ks = t >> 8;
  { // embed layer, K-slice 196, depth-2 weight prefetch
    const int kb = ks * 196;
    const float* Wc = Wemb + (size_t)kb * EDIM + j;
    float w0[4], w1r[4], w2r[4];
    ldw4(w0, Wc); ldw4(w1r, Wc + 4 * EDIM);
    float a[4] = {0.f,0.f,0.f,0.f};
#pragma unroll 7
    for (int kk = 0; kk < 196; kk += 4) {
      if (kk + 8 < 196) ldw4(w2r, Wc + (size_t)(kk + 8) * EDIM);
      const int k = kb + kk;
#pragma unroll
      for (int i = 0; i < 4; i++) {
        const float4 s4 = *(const float4*)&XS[i * INDIM + k];
        a[i] = fmaf(s4.x, w0[0], a[i]); a[i] = fmaf(s4.y, w0[1], a[i]);
        a[i] = fmaf(s4.z, w0[2], a[i]); a[i] = fmaf(s4.w, w0[3], a[i]);
      }
      ROT_W();
    }
#pragma unroll
    for (int q = 0; q < 4; q++) P[ks][j][q] = a[q];
  }
  __syncthreads();
  { const int j2 = t & 255, i = t >> 8;
    float s = P[0][j2][i] + P[1][j2][i] + P[2][j2][i] + P[3][j2][i] + bemb[j2];
    SS[i * EDIM + j2] = s;
    const size_t idx = (size_t)(b0 + i) * EDIM + j2;
    state[idx] = s; initial[idx] = s;
  }
  __syncthreads();

  // ---- A0 on SS ----
  { const int kb = ks * 64;
    const float* Wc = aW1 + (size_t)kb * EDIM + j;
    float w0[4], w1r[4], w2r[4];
    ldw4(w0, Wc); ldw4(w1r, Wc + 4 * EDIM);
    float a[4] = {0.f,0.f,0.f,0.f};
#pragma unroll
    for (int kk = 0; kk < 64; kk += 4) {
      if (kk + 8 < 64) ldw4(w2r, Wc + (size_t)(kk + 8) * EDIM);
      const int k = kb + kk;
#pragma unroll
      for (int i = 0; i < 4; i++) {
        const float4 s4 = *(const float4*)&SS[i * EDIM + k];
        a[i] = fmaf(s4.x, w0[0], a[i]); a[i] = fmaf(s4.y, w0[1], a[i]);
        a[i] = fmaf(s4.z, w0[2], a[i]); a[i] = fmaf(s4.w, w0[3], a[i]);
      }
      ROT_W();
    }
#pragma unroll
    for (int q = 0; q < 4; q++) P[ks][j][q] = a[q];
  }
  __syncthreads();
  { const int j2 = t & 255, i = t >> 8;
    float s = P[0][j2][i] + P[1][j2][i] + P[2][j2][i] + P[3][j2][i] + ab1[j2];
    H[j2][i] = fmaxf(s, 0.f);
  }
  __syncthreads();
  { const int c = t & 15, i = (t >> 4) & 3, ksl = t >> 6;   // 16 slices of 16
    float a2 = 0.f;
    if (c < 12) {
      const int k0 = ksl * 16;
#pragma unroll 4
      for (int k = k0; k < k0 + 16; k++)
        a2 = fmaf(H[k][i], aW2[k * 12 + c], a2);
    }
    P2[ksl][i][c] = a2;
  }
  __syncthreads();
  if (t < 48) {
    const int i = t / 12, c = t % 12;
    float s = 0.f;
#pragma unroll
    for (int w = 0; w < 16; w++) s += P2[w][i][c];
    vals[i][c] = s + ab2[c] + gumbel_val(0, b0 + i, c);
  }
  __syncthreads();
  if (t < 4) nn_all[b0 + t] = addr_argmax(vals[t]);   // step 0: no exit logic
}

// ============ A_s (s=1..4): addr MLP for 4 rows/WG, frozen rows gated ============
__global__ __launch_bounds__(1024, 4) void k_addr(
    const float* __restrict__ state,
    const float* __restrict__ aW1, const float* __restrict__ ab1,
    const float* __restrict__ aW2, const float* __restrict__ ab2,
    const int* __restrict__ nn_prev, int* __restrict__ nn_out, int step) {
  __shared__ float XS[4 * EDIM];
  __shared__ float P[4][256][5];
  __shared__ float H[EDIM][4];
  __shared__ float P2[16][4][16];
  __shared__ float vals[4][12];
  const int t = threadIdx.x, b0 = blockIdx.x * 4;

  XS[t] = state[(size_t)b0 * EDIM + t];
  __syncthreads();

  const int j = t & 255, ks = t >> 8;
  { const int kb = ks * 64;
    const float* Wc = aW1 + (size_t)kb * EDIM + j;
    float w0[4], w1r[4], w2r[4];
    ldw4(w0, Wc); ldw4(w1r, Wc + 4 * EDIM);
    float a[4] = {0.f,0.f,0.f,0.f};
#pragma unroll
    for (int kk = 0; kk < 64; kk += 4) {
      if (kk + 8 < 64) ldw4(w2r, Wc + (size_t)(kk + 8) * EDIM);
      const int k = kb + kk;
#pragma unroll
      for (int i = 0; i < 4; i++) {
        const float4 s4 = *(const float4*)&XS[i * EDIM + k];
        a[i] = fmaf(s4.x, w0[0], a[i]); a[i] = fmaf(s4.y, w0[1], a[i]);
        a[i] = fmaf(s4.z, w0[2], a[i]); a[i] = fmaf(s4.w, w0[3], a[i]);
      }
      ROT_W();
    }
#pragma unroll
    for (int q = 0; q < 4; q++) P[ks][j][q] = a[q];
  }
  __syncthreads();
  { const int j2 = t & 255, i = t >> 8;
    float s = P[0][j2][i] + P[1][j2][i] + P[2][j2][i] + P[3][j2][i] + ab1[j2];
    H[j2][i] = fmaxf(s, 0.f);
  }
  __syncthreads();
  { const int c = t & 15, i = (t >> 4) & 3, ksl = t >> 6;
    float a2 = 0.f;
    if (c < 12) {
      const int k0 = ksl * 16;
#pragma unroll 4
      for (int k = k0; k < k0 + 16; k++)
        a2 = fmaf(H[k][i], aW2[k * 12 + c], a2);
    }
    P2[ksl][i][c] = a2;
  }
  __syncthreads();
  if (t < 48) {
    const int i = t / 12, c = t % 12;
    float s = 0.f;
#pragma unroll
    for (int w = 0; w < 16; w++) s += P2[w][i][c];
    vals[i][c] = s + ab2[c] + gumbel_val(step, b0 + i, c);
  }
  __syncthreads();
  if (t < 4) {
    const int b = b0 + t;
    int nxt;
    if (nn_prev[b] < 0) nxt = -1;                      // already frozen
    else {
      const int nn = addr_argmax(vals[t]);
      nxt = (step < 4 && nn == 0) ? -1 : nn;           // exit -> freeze
    }
    nn_out[b] = nxt;
  }
}

// ============ B_j: routed block eval in-place, CHUNK=8, XCD-swizzled ============
__global__ __launch_bounds__(1024, 4) void k_blocks(
    float* __restrict__ state,
    const float* __restrict__ W1, const float* __restrict__ b1,
    const float* __restrict__ W2, const float* __restrict__ b2,
    const int* __restrict__ nnj) {
  __shared__ float XS[8 * EDIM];
  __shared__ float P[4][EDIM][9];
  __shared__ float H[EDIM][12];
  __shared__ int hist[64];
  __shared__ int meta[4];
  __shared__ int rowsl[8];
  __shared__ float denom[8];
  __shared__ int wcnt[16], wbase[16];
  const int t = threadIdx.x;
  const int c = ((blockIdx.x & 7) * 24) + (blockIdx.x >> 3);   // XCD swizzle (grid 192)

  if (t < 64) hist[t] = 0;
  if (t < 8) rowsl[t] = 0;
  __syncthreads();
  const int vmy = nnj[t];
  if (vmy >= 0) atomicAdd(&hist[vmy], 1);
  __syncthreads();
  if (t < 64) {
    const int cnt = hist[t];
    const int nch = (cnt + 7) >> 3;
    int icnt = cnt, inch = nch;
#pragma unroll
    for (int d = 1; d < 64; d <<= 1) {
      int t1 = __shfl_up(icnt, d), t2 = __shfl_up(inch, d);
      if (t >= d) { icnt += t1; inch += t2; }
    }
    const int ench = inch - nch;
    if (t == 63) meta[3] = inch;
    if (c >= ench && c < ench + nch) {
      meta[0] = t; meta[1] = c - ench;
      meta[2] = min(8, cnt - (c - ench) * 8);
    }
  }
  __syncthreads();
  if (c >= meta[3]) return;
  const int n = meta[0], local = meta[1], m = meta[2];

  { const bool flag = (vmy == n);
    const unsigned long long bal = __ballot(flag);
    const int wid = t >> 6, lane = t & 63;
    if (lane == 0) wcnt[wid] = __popcll(bal);
    __syncthreads();
    if (t == 0) { int s = 0; for (int w = 0; w < 16; w++) { wbase[w] = s; s += wcnt[w]; } }
    __syncthreads();
    if (flag) {
      const int rank = wbase[wid] + __popcll(bal & ((1ull << lane) - 1ull));
      const int r0 = local * 8;
      if (rank >= r0 && rank < r0 + 8) rowsl[rank - r0] = t;
    }
    __syncthreads();
  }

  if (t < 512) {
    const int i = t >> 6, q = t & 63;
    const int row = rowsl[min(i, m - 1)] & 1023;
    const float4 v = *(const float4*)(state + (size_t)row * EDIM + q * 4);
    ((float4*)XS)[t] = v;
    float sq = v.x*v.x + v.y*v.y + v.z*v.z + v.w*v.w;
#pragma unroll
    for (int d = 32; d >= 1; d >>= 1) sq += __shfl_xor(sq, d);
    if (q == 0) denom[i] = sqrtf(sq) + 1e-6f;
  }
  __syncthreads();

  const int j = t & 255, ks = t >> 8;
  const int kb = ks * 64;
  { // layer 1, depth-2 prefetch
    const float* Wc = W1 + (size_t)n * EDIM * EDIM + (size_t)kb * EDIM + j;
    float w0[4], w1r[4], w2r[4];
    ldw4(w0, Wc); ldw4(w1r, Wc + 4 * EDIM);
    float a[8] = {0.f,0.f,0.f,0.f,0.f,0.f,0.f,0.f};
#pragma unroll
    for (int kk = 0; kk < 64; kk += 4) {
      if (kk + 8 < 64) ldw4(w2r, Wc + (size_t)(kk + 8) * EDIM);
      const int k = kb + kk;
#pragma unroll
      for (int i = 0; i < 8; i++) {
        const float4 s4 = *(const float4*)&XS[i * EDIM + k];
        a[i] = fmaf(s4.x, w0[0], a[i]); a[i] = fmaf(s4.y, w0[1], a[i]);
        a[i] = fmaf(s4.z, w0[2], a[i]); a[i] = fmaf(s4.w, w0[3], a[i]);
      }
      ROT_W();
    }
#pragma unroll
    for (int q = 0; q < 8; q++) P[ks][j][q] = a[q];
  }
  __syncthreads();
  { const int j2 = t & 255, ih = t >> 8;
    const float bb = b1[(size_t)n * EDIM + j2];
#pragma unroll
    for (int qq = 0; qq < 2; qq++) {
      const int i = ih + qq * 4;
      float s = P[0][j2][i] + P[1][j2][i] + P[2][j2][i] + P[3][j2][i] + bb;
      H[j2][i] = fmaxf(s, 0.f);
    }
  }
  __syncthreads();
  { // layer 2, depth-2 prefetch (FMA order: k ascending, 8 rows per k)
    const float* Wc = W2 + (size_t)n * EDIM * EDIM + (size_t)kb * EDIM + j;
    float w0[4], w1r[4], w2r[4];
    ldw4(w0, Wc); ldw4(w1r, Wc + 4 * EDIM);
    float a[8] = {0.f,0.f,0.f,0.f,0.f,0.f,0.f,0.f};
#pragma unroll
    for (int kk = 0; kk < 64; kk += 4) {
      if (kk + 8 < 64) ldw4(w2r, Wc + (size_t)(kk + 8) * EDIM);
#pragma unroll
      for (int q = 0; q < 4; q++) {
        const int k = kb + kk + q;
        const float4 h0 = *(const float4*)&H[k][0];
        const float4 h1 = *(const float4*)&H[k][4];
        const float w = w0[q];
        a[0] = fmaf(h0.x, w, a[0]); a[1] = fmaf(h0.y, w, a[1]);
        a[2] = fmaf(h0.z, w, a[2]); a[3] = fmaf(h0.w, w, a[3]);
        a[4] = fmaf(h1.x, w, a[4]); a[5] = fmaf(h1.y, w, a[5]);
        a[6] = fmaf(h1.z, w, a[6]); a[7] = fmaf(h1.w, w, a[7]);
      }
      ROT_W();
    }
#pragma unroll
    for (int q = 0; q < 8; q++) P[ks][j][q] = a[q];
  }
  __syncthreads();
  { const int col = t & 255, ih = t >> 8;
    const float bb2 = b2[(size_t)n * EDIM + col];
#pragma unroll
    for (int qq = 0; qq < 2; qq++) {
      const int i = ih + qq * 4;
      if (i < m) {
        float s = P[0][col][i] + P[1][col][i] + P[2][col][i] + P[3][col][i] + bb2;
        const int row = rowsl[i] & 1023;
        state[(size_t)row * EDIM + col] = fmaxf(s, 0.f) / denom[i];
      }
    }
  }
}

// ============ B4 + head ============
__global__ __launch_bounds__(1024, 4) void k_block_final(
    const float* __restrict__ state,
    const float* __restrict__ W1, const float* __restrict__ b1,
    const float* __restrict__ W2, const float* __restrict__ b2,
    const float* __restrict__ initial,
    const float* __restrict__ oW1, const float* __restrict__ ob1,
    const float* __restrict__ oW2, const float* __restrict__ ob2,
    const int* __restrict__ nn4, float* __restrict__ out) {
  __shared__ float XS[8 * EDIM];
  __shared__ float P[4][EDIM][9];
  __shared__ float H[EDIM][12];
  __shared__ float P2[8][8][16];
  __shared__ int hist[64];
  __shared__ int meta[4];
  __shared__ int rowsl[8];
  __shared__ float denom[8];
  __shared__ int wcnt[16], wbase[16];
  const int t = threadIdx.x;
  const int c = ((blockIdx.x & 7) * 24) + (blockIdx.x >> 3);

  if (t < 64) hist[t] = 0;
  if (t < 8) rowsl[t] = 0;
  __syncthreads();
  int vmy = nn4[t];
  if (vmy < 0) vmy = 0;                 // exited rows re-enter at origin
  atomicAdd(&hist[vmy], 1);
  __syncthreads();
  if (t < 64) {
    const int cnt = hist[t];
    const int nch = (cnt + 7) >> 3;
    int icnt = cnt, inch = nch;
#pragma unroll
    for (int d = 1; d < 64; d <<= 1) {
      int t1 = __shfl_up(icnt, d), t2 = __shfl_up(inch, d);
      if (t >= d) { icnt += t1; inch += t2; }
    }
    const int ench = inch - nch;
    if (t == 63) meta[3] = inch;
    if (c >= ench && c < ench + nch) {
      meta[0] = t; meta[1] = c - ench;
      meta[2] = min(8, cnt - (c - ench) * 8);
    }
  }
  __syncthreads();
  if (c >= meta[3]) return;
  const int n = meta[0], local = meta[1], m = meta[2];

  { const bool flag = (vmy == n);
    const unsigned long long bal = __ballot(flag);
    const int wid = t >> 6, lane = t & 63;
    if (lane == 0) wcnt[wid] = __popcll(bal);
    __syncthreads();
    if (t == 0) { int s = 0; for (int w = 0; w < 16; w++) { wbase[w] = s; s += wcnt[w]; } }
    __syncthreads();
    if (flag) {
      const int rank = wbase[wid] + __popcll(bal & ((1ull << lane) - 1ull));
      const int r0 = local * 8;
      if (rank >= r0 && rank < r0 + 8) rowsl[rank - r0] = t;
    }
    __syncthreads();
  }

  if (t < 512) {
    const int i = t >> 6, q = t & 63;
    const int row = rowsl[min(i, m - 1)] & 1023;
    const float4 v = *(const float4*)(state + (size_t)row * EDIM + q * 4);
    ((float4*)XS)[t] = v;
    float sq = v.x*v.x + v.y*v.y + v.z*v.z + v.w*v.w;
#pragma unroll
    for (int d = 32; d >= 1; d >>= 1) sq += __shfl_xor(sq, d);
    if (q == 0) denom[i] = sqrtf(sq) + 1e-6f;
  }
  __syncthreads();

  const int j = t & 255, ks = t >> 8;
  const int kb = ks * 64;
  { const float* Wc = W1 + (size_t)n * EDIM * EDIM + (size_t)kb * EDIM + j;
    float w0[4], w1r[4], w2r[4];
    ldw4(w0, Wc); ldw4(w1r, Wc + 4 * EDIM);
    float a[8] = {0.f,0.f,0.f,0.f,0.f,0.f,0.f,0.f};
#pragma unroll
    for (int kk = 0; kk < 64; kk += 4) {
      if (kk + 8 < 64) ldw4(w2r, Wc + (size_t)(kk + 8) * EDIM);
      const int k = kb + kk;
#pragma unroll
      for (int i = 0; i < 8; i++) {
        const float4 s4 = *(const float4*)&XS[i * EDIM + k];
        a[i] = fmaf(s4.x, w0[0], a[i]); a[i] = fmaf(s4.y, w0[1], a[i]);
        a[i] = fmaf(s4.z, w0[2], a[i]); a[i] = fmaf(s4.w, w0[3], a[i]);
      }
      ROT_W();
    }
#pragma unroll
    for (int q = 0; q < 8; q++) P[ks][j][q] = a[q];
  }
  __syncthreads();
  { const int j2 = t & 255, ih = t >> 8;
    const float bb = b1[(size_t)n * EDIM + j2];
#pragma unroll
    for (int qq = 0; qq < 2; qq++) {
      const int i = ih + qq * 4;
      float s = P[0][j2][i] + P[1][j2][i] + P[2][j2][i] + P[3][j2][i] + bb;
      H[j2][i] = fmaxf(s, 0.f);
    }
  }
  __syncthreads();
  { const float* Wc = W2 + (size_t)n * EDIM * EDIM + (size_t)kb * EDIM + j;
    float w0[4], w1r[4], w2r[4];
    ldw4(w0, Wc); ldw4(w1r, Wc + 4 * EDIM);
    float a[8] = {0.f,0.f,0.f,0.f,0.f,0.f,0.f,0.f};
#pragma unroll
    for (int kk = 0; kk < 64; kk += 4) {
      if (kk + 8 < 64) ldw4(w2r, Wc + (size_t)(kk + 8) * EDIM);
#pragma unroll
      for (int q = 0; q < 4; q++) {
        const int k = kb + kk + q;
        const float4 h0 = *(const float4*)&H[k][0];
        const float4 h1 = *(const float4*)&H[k][4];
        const float w = w0[q];
        a[0] = fmaf(h0.x, w, a[0]); a[1] = fmaf(h0.y, w, a[1]);
        a[2] = fmaf(h0.z, w, a[2]); a[3] = fmaf(h0.w, w, a[3]);
        a[4] = fmaf(h1.x, w, a[4]); a[5] = fmaf(h1.y, w, a[5]);
        a[6] = fmaf(h1.z, w, a[6]); a[7] = fmaf(h1.w, w, a[7]);
      }
      ROT_W();
    }
#pragma unroll
    for (int q = 0; q < 8; q++) P[ks][j][q] = a[q];
  }
  __syncthreads();
  { const int col = t & 255, ih = t >> 8;
    const float bb2 = b2[(size_t)n * EDIM + col];
#pragma unroll
    for (int qq = 0; qq < 2; qq++) {
      const int i = ih + qq * 4;
      if (i < m) {
        float s = P[0][col][i] + P[1][col][i] + P[2][col][i] + P[3][col][i] + bb2;
        float v = fmaxf(s, 0.f) / denom[i];
        const int row = rowsl[i] & 1023;
        v += initial[(size_t)row * EDIM + col];
        XS[i * EDIM + col] = v;          // head input
      }
    }
  }
  __syncthreads();

  // ---- head ----
  { const float* Wc = oW1 + (size_t)kb * EDIM + j;
    float w0[4], w1r[4], w2r[4];
    ldw4(w0, Wc); ldw4(w1r, Wc + 4 * EDIM);
    float a[8] = {0.f,0.f,0.f,0.f,0.f,0.f,0.f,0.f};
#pragma unroll
    for (int kk = 0; kk < 64; kk += 4) {
      if (kk + 8 < 64) ldw4(w2r, Wc + (size_t)(kk + 8) * EDIM);
      const int k = kb + kk;
#pragma unroll
      for (int i = 0; i < 8; i++) {
        const float4 s4 = *(const float4*)&XS[i * EDIM + k];
        a[i] = fmaf(s4.x, w0[0], a[i]); a[i] = fmaf(s4.y, w0[1], a[i]);
        a[i] = fmaf(s4.z, w0[2], a[i]); a[i] = fmaf(s4.w, w0[3], a[i]);
      }
      ROT_W();
    }
#pragma unroll
    for (int q = 0; q < 8; q++) P[ks][j][q] = a[q];
  }
  __syncthreads();
  { const int j2 = t & 255, ih = t >> 8;
    const float bb = ob1[j2];
#pragma unroll
    for (int qq = 0; qq < 2; qq++) {
      const int i = ih + qq * 4;
      float s = P[0][j2][i] + P[1][j2][i] + P[2][j2][i] + P[3][j2][i] + bb;
      H[j2][i] = fmaxf(s, 0.f);
    }
  }
  __syncthreads();
  { const int cc = t & 15, i = (t >> 4) & 7, ksl = t >> 7;   // 8 slices of 32
    float a2 = 0.f;
    if (cc < 10) {
      const int k0 = ksl * 32;
#pragma unroll 4
      for (int k = k0; k < k0 + 32; k++)
        a2 = fmaf(H[k][i], oW2[k * 10 + cc], a2);
    }
    P2[ksl][i][cc] = a2;
  }
  __syncthreads();
  if (t < 80) {
    const int i = t / 10, cc = t % 10;
    if (i < m) {
      float s = 0.f;
#pragma unroll
      for (int w = 0; w < 8; w++) s += P2[w][i][cc];
      const int row = rowsl[i] & 1023;
      out[(size_t)row * 10 + cc] = s + ob2[cc];
    }
  }
}

// ---------------- launch: 10 dispatches ----------------
extern "C" void kernel_launch(void* const* d_in, const int* in_sizes, int n_in,
                              void* d_out, int out_size, void* d_ws, size_t ws_size,
                              hipStream_t stream) {
  const float* x    = (const float*)d_in[0];
  const float* Wemb = (const float*)d_in[1];
  const float* bemb = (const float*)d_in[2];
  const float* stW1 = (const float*)d_in[3];
  const float* stb1 = (const float*)d_in[4];
  const float* stW2 = (const float*)d_in[5];
  const float* stb2 = (const float*)d_in[6];
  const float* aW1  = (const float*)d_in[7];
  const float* ab1  = (const float*)d_in[8];
  const float* aW2  = (const float*)d_in[9];
  const float* ab2  = (const float*)d_in[10];
  const float* oW1  = (const float*)d_in[11];
  const float* ob1  = (const float*)d_in[12];
  const float* oW2  = (const float*)d_in[13];
  const float* ob2  = (const float*)d_in[14];
  float* out = (float*)d_out;

  char* ws = (char*)d_ws;
  auto alloc = [&](size_t bytes) { char* p = ws; ws += (bytes + 255) & ~(size_t)255; return p; };
  float* state   = (float*)alloc((size_t)BATCH * EDIM * 4);
  float* initial = (float*)alloc((size_t)BATCH * EDIM * 4);
  int*   nn_all  = (int*)alloc(5 * BATCH * 4);

  k_embed_a0<<<BATCH / 4, 1024, 0, stream>>>(x, Wemb, bemb, aW1, ab1, aW2, ab2,
                                             state, initial, nn_all);
  for (int j = 0; j < 4; j++) {
    k_blocks<<<GRID_B, 1024, 0, stream>>>(state, stW1, stb1, stW2, stb2,
                                          nn_all + j * BATCH);
    k_addr<<<BATCH / 4, 1024, 0, stream>>>(state, aW1, ab1, aW2, ab2,
                                           nn_all + j * BATCH,
                                           nn_all + (j + 1) * BATCH, j + 1);
  }
  k_block_final<<<GRID_B, 1024, 0, stream>>>(state, stW1, stb1, stW2, stb2,
                                             initial, oW1, ob1, oW2, ob2,
                                             nn_all + 4 * BATCH, out);
}

// Round 7
// 280.611 us; speedup vs baseline: 1.2010x; 1.2010x over previous
//
#include <hip/hip_runtime.h>
#include <stdint.h>

// SelfOrganizingBrain: B=1024, IN=784, E=256, NCLS=10, N=64 blocks, NJUMPS=4.
// R6: R5's scratch disaster fixed. Evidence: k_embed_a0 WRITE_SIZE=231MB
// (logical 2MB) -> rotating weight arrays passed by pointer spilled to
// scratch. R6 keeps the 10-dispatch structure but batches weight loads as
// fully-unrolled constant-indexed locals (16-28 in flight), outer loop
// #pragma unroll 1 (VGPR control), no rotation, no pointer-passing.
// FMA order identical to R2/R4/R5 (bit-exact logits -> same gumbel argmax).

#define BATCH 1024
#define EDIM  256
#define INDIM 784
#define GRID_B 192   // max chunks = sum ceil(cnt_n/8) <= 184

// ---------------- threefry2x32 (exact JAX semantics, validated R0-R5) ----------------
__host__ __device__ inline uint32_t rotl32(uint32_t x, uint32_t d) {
  return (x << d) | (x >> (32u - d));
}
__host__ __device__ inline void threefry2x32(uint32_t k0, uint32_t k1,
                                             uint32_t x0, uint32_t x1,
                                             uint32_t* o0, uint32_t* o1) {
  uint32_t ks2 = k0 ^ k1 ^ 0x1BD11BDAu;
  x0 += k0; x1 += k1;
#define TF_R(a) { x0 += x1; x1 = rotl32(x1, a); x1 ^= x0; }
  TF_R(13) TF_R(15) TF_R(26) TF_R(6)   x0 += k1;  x1 += ks2 + 1u;
  TF_R(17) TF_R(29) TF_R(16) TF_R(24)  x0 += ks2; x1 += k0  + 2u;
  TF_R(13) TF_R(15) TF_R(26) TF_R(6)   x0 += k0;  x1 += k1  + 3u;
  TF_R(17) TF_R(29) TF_R(16) TF_R(24)  x0 += k1;  x1 += ks2 + 4u;
  TF_R(13) TF_R(15) TF_R(26) TF_R(6)   x0 += ks2; x1 += k0  + 5u;
#undef TF_R
  *o0 = x0; *o1 = x1;
}
__device__ inline uint32_t jax_bits12288(uint32_t k0, uint32_t k1, uint32_t L) {
  uint32_t o0, o1;
  if (L < 6144u) { threefry2x32(k0, k1, L, L + 6144u, &o0, &o1); return o0; }
  else           { threefry2x32(k0, k1, L - 6144u, L, &o0, &o1); return o1; }
}
__device__ inline float jax_uniform(uint32_t bits) {
  const float minv = 1e-6f;
  const float maxv = (float)(1.0 - 1e-06);
  const float span = maxv - minv;
  uint32_t fb = (bits >> 9) | 0x3f800000u;
  float f = __uint_as_float(fb) - 1.0f;
  float u = __fadd_rn(__fmul_rn(f, span), minv);
  return fmaxf(minv, u);
}
__device__ inline float gumbel_val(int s, int b, int c) {
  uint32_t fk0, fk1;
  threefry2x32(0u, 42u, 0u, (uint32_t)s, &fk0, &fk1);   // fold_in(key(42), s)
  const uint32_t L = (uint32_t)(b * 12 + c);
  const float u = jax_uniform(jax_bits12288(fk0, fk1, L));
  return -logf(-logf(u));
}
__device__ inline int addr_argmax(const float* v) {
  int i0 = 0, i1 = 0, i2 = 0;
  { float b = v[0];
    for (int c = 1; c < 4; c++) { float x = v[c];     if (x > b) { b = x; i0 = c; } } }
  { float b = v[4];
    for (int c = 1; c < 4; c++) { float x = v[4 + c]; if (x > b) { b = x; i1 = c; } } }
  { float b = v[8];
    for (int c = 1; c < 4; c++) { float x = v[8 + c]; if (x > b) { b = x; i2 = c; } } }
  return i0 * 16 + i1 * 4 + i2;
}

// ============ E + A0: embed 4 rows/WG + addr step 0 ============
__global__ __launch_bounds__(1024, 4) void k_embed_a0(
    const float* __restrict__ x, const float* __restrict__ Wemb,
    const float* __restrict__ bemb,
    const float* __restrict__ aW1, const float* __restrict__ ab1,
    const float* __restrict__ aW2, const float* __restrict__ ab2,
    float* __restrict__ state, float* __restrict__ initial,
    int* __restrict__ nn_all) {
  __shared__ float XS[4 * INDIM];
  __shared__ float P[4][256][5];
  __shared__ float SS[4 * EDIM];
  __shared__ float H[EDIM][4];
  __shared__ float P2[16][4][16];
  __shared__ float vals[4][12];
  const int t = threadIdx.x, b0 = blockIdx.x * 4;

  { const float4* src = (const float4*)(x + (size_t)b0 * INDIM);
    float4* dst = (float4*)XS;
    for (int p = t; p < INDIM; p += 1024) dst[p] = src[p];
  }
  __syncthreads();

  const int j = t & 255, ks = t >> 8;
  { // embed layer: K-slice 196 = 7 batches of 28 loads
    const int kb = ks * 196;
    const float* Wc = Wemb + (size_t)kb * EDIM + j;
    float a[4] = {0.f,0.f,0.f,0.f};
#pragma unroll 1
    for (int kk = 0; kk < 196; kk += 28) {
      float wv[28];
#pragma unroll
      for (int u = 0; u < 28; u++) wv[u] = Wc[(size_t)(kk + u) * EDIM];
#pragma unroll
      for (int u4 = 0; u4 < 28; u4 += 4) {
        const int k = kb + kk + u4;
#pragma unroll
        for (int i = 0; i < 4; i++) {
          const float4 s4 = *(const float4*)&XS[i * INDIM + k];
          a[i] = fmaf(s4.x, wv[u4+0], a[i]); a[i] = fmaf(s4.y, wv[u4+1], a[i]);
          a[i] = fmaf(s4.z, wv[u4+2], a[i]); a[i] = fmaf(s4.w, wv[u4+3], a[i]);
        }
      }
    }
#pragma unroll
    for (int q = 0; q < 4; q++) P[ks][j][q] = a[q];
  }
  __syncthreads();
  { const int j2 = t & 255, i = t >> 8;
    float s = P[0][j2][i] + P[1][j2][i] + P[2][j2][i] + P[3][j2][i] + bemb[j2];
    SS[i * EDIM + j2] = s;
    const size_t idx = (size_t)(b0 + i) * EDIM + j2;
    state[idx] = s; initial[idx] = s;
  }
  __syncthreads();

  // ---- A0 on SS: K-slice 64 = 4 batches of 16 ----
  { const int kb = ks * 64;
    const float* Wc = aW1 + (size_t)kb * EDIM + j;
    float a[4] = {0.f,0.f,0.f,0.f};
#pragma unroll 1
    for (int kk = 0; kk < 64; kk += 16) {
      float wv[16];
#pragma unroll
      for (int u = 0; u < 16; u++) wv[u] = Wc[(size_t)(kk + u) * EDIM];
#pragma unroll
      for (int u4 = 0; u4 < 16; u4 += 4) {
        const int k = kb + kk + u4;
#pragma unroll
        for (int i = 0; i < 4; i++) {
          const float4 s4 = *(const float4*)&SS[i * EDIM + k];
          a[i] = fmaf(s4.x, wv[u4+0], a[i]); a[i] = fmaf(s4.y, wv[u4+1], a[i]);
          a[i] = fmaf(s4.z, wv[u4+2], a[i]); a[i] = fmaf(s4.w, wv[u4+3], a[i]);
        }
      }
    }
#pragma unroll
    for (int q = 0; q < 4; q++) P[ks][j][q] = a[q];
  }
  __syncthreads();
  { const int j2 = t & 255, i = t >> 8;
    float s = P[0][j2][i] + P[1][j2][i] + P[2][j2][i] + P[3][j2][i] + ab1[j2];
    H[j2][i] = fmaxf(s, 0.f);
  }
  __syncthreads();
  { const int c = t & 15, i = (t >> 4) & 3, ksl = t >> 6;   // 16 slices of 16
    float a2 = 0.f;
    if (c < 12) {
      const int k0 = ksl * 16;
#pragma unroll 4
      for (int k = k0; k < k0 + 16; k++)
        a2 = fmaf(H[k][i], aW2[k * 12 + c], a2);
    }
    P2[ksl][i][c] = a2;
  }
  __syncthreads();
  if (t < 48) {
    const int i = t / 12, c = t % 12;
    float s = 0.f;
#pragma unroll
    for (int w = 0; w < 16; w++) s += P2[w][i][c];
    vals[i][c] = s + ab2[c] + gumbel_val(0, b0 + i, c);
  }
  __syncthreads();
  if (t < 4) nn_all[b0 + t] = addr_argmax(vals[t]);   // step 0: no exit logic
}

// ============ A_s (s=1..4): addr MLP, 4 rows/WG, frozen rows gated ============
__global__ __launch_bounds__(1024, 4) void k_addr(
    const float* __restrict__ state,
    const float* __restrict__ aW1, const float* __restrict__ ab1,
    const float* __restrict__ aW2, const float* __restrict__ ab2,
    const int* __restrict__ nn_prev, int* __restrict__ nn_out, int step) {
  __shared__ float XS[4 * EDIM];
  __shared__ float P[4][256][5];
  __shared__ float H[EDIM][4];
  __shared__ float P2[16][4][16];
  __shared__ float vals[4][12];
  const int t = threadIdx.x, b0 = blockIdx.x * 4;

  XS[t] = state[(size_t)b0 * EDIM + t];
  __syncthreads();

  const int j = t & 255, ks = t >> 8;
  { const int kb = ks * 64;
    const float* Wc = aW1 + (size_t)kb * EDIM + j;
    float a[4] = {0.f,0.f,0.f,0.f};
#pragma unroll 1
    for (int kk = 0; kk < 64; kk += 16) {
      float wv[16];
#pragma unroll
      for (int u = 0; u < 16; u++) wv[u] = Wc[(size_t)(kk + u) * EDIM];
#pragma unroll
      for (int u4 = 0; u4 < 16; u4 += 4) {
        const int k = kb + kk + u4;
#pragma unroll
        for (int i = 0; i < 4; i++) {
          const float4 s4 = *(const float4*)&XS[i * EDIM + k];
          a[i] = fmaf(s4.x, wv[u4+0], a[i]); a[i] = fmaf(s4.y, wv[u4+1], a[i]);
          a[i] = fmaf(s4.z, wv[u4+2], a[i]); a[i] = fmaf(s4.w, wv[u4+3], a[i]);
        }
      }
    }
#pragma unroll
    for (int q = 0; q < 4; q++) P[ks][j][q] = a[q];
  }
  __syncthreads();
  { const int j2 = t & 255, i = t >> 8;
    float s = P[0][j2][i] + P[1][j2][i] + P[2][j2][i] + P[3][j2][i] + ab1[j2];
    H[j2][i] = fmaxf(s, 0.f);
  }
  __syncthreads();
  { const int c = t & 15, i = (t >> 4) & 3, ksl = t >> 6;
    float a2 = 0.f;
    if (c < 12) {
      const int k0 = ksl * 16;
#pragma unroll 4
      for (int k = k0; k < k0 + 16; k++)
        a2 = fmaf(H[k][i], aW2[k * 12 + c], a2);
    }
    P2[ksl][i][c] = a2;
  }
  __syncthreads();
  if (t < 48) {
    const int i = t / 12, c = t % 12;
    float s = 0.f;
#pragma unroll
    for (int w = 0; w < 16; w++) s += P2[w][i][c];
    vals[i][c] = s + ab2[c] + gumbel_val(step, b0 + i, c);
  }
  __syncthreads();
  if (t < 4) {
    const int b = b0 + t;
    int nxt;
    if (nn_prev[b] < 0) nxt = -1;                      // already frozen
    else {
      const int nn = addr_argmax(vals[t]);
      nxt = (step < 4 && nn == 0) ? -1 : nn;           // exit -> freeze
    }
    nn_out[b] = nxt;
  }
}

// ============ B_j: routed block eval in-place, CHUNK=8, XCD-swizzled ============
__global__ __launch_bounds__(1024, 4) void k_blocks(
    float* __restrict__ state,
    const float* __restrict__ W1, const float* __restrict__ b1,
    const float* __restrict__ W2, const float* __restrict__ b2,
    const int* __restrict__ nnj) {
  __shared__ float XS[8 * EDIM];
  __shared__ float P[4][EDIM][9];
  __shared__ float H[EDIM][12];
  __shared__ int hist[64];
  __shared__ int meta[4];
  __shared__ int rowsl[8];
  __shared__ float denom[8];
  __shared__ int wcnt[16], wbase[16];
  const int t = threadIdx.x;
  const int c = ((blockIdx.x & 7) * 24) + (blockIdx.x >> 3);   // XCD swizzle

  if (t < 64) hist[t] = 0;
  if (t < 8) rowsl[t] = 0;
  __syncthreads();
  const int vmy = nnj[t];
  if (vmy >= 0) atomicAdd(&hist[vmy], 1);
  __syncthreads();
  if (t < 64) {
    const int cnt = hist[t];
    const int nch = (cnt + 7) >> 3;
    int icnt = cnt, inch = nch;
#pragma unroll
    for (int d = 1; d < 64; d <<= 1) {
      int t1 = __shfl_up(icnt, d), t2 = __shfl_up(inch, d);
      if (t >= d) { icnt += t1; inch += t2; }
    }
    const int ench = inch - nch;
    if (t == 63) meta[3] = inch;
    if (c >= ench && c < ench + nch) {
      meta[0] = t; meta[1] = c - ench;
      meta[2] = min(8, cnt - (c - ench) * 8);
    }
  }
  __syncthreads();
  if (c >= meta[3]) return;
  const int n = meta[0], local = meta[1], m = meta[2];

  { const bool flag = (vmy == n);
    const unsigned long long bal = __ballot(flag);
    const int wid = t >> 6, lane = t & 63;
    if (lane == 0) wcnt[wid] = __popcll(bal);
    __syncthreads();
    if (t == 0) { int s = 0; for (int w = 0; w < 16; w++) { wbase[w] = s; s += wcnt[w]; } }
    __syncthreads();
    if (flag) {
      const int rank = wbase[wid] + __popcll(bal & ((1ull << lane) - 1ull));
      const int r0 = local * 8;
      if (rank >= r0 && rank < r0 + 8) rowsl[rank - r0] = t;
    }
    __syncthreads();
  }

  if (t < 512) {
    const int i = t >> 6, q = t & 63;
    const int row = rowsl[min(i, m - 1)] & 1023;
    const float4 v = *(const float4*)(state + (size_t)row * EDIM + q * 4);
    ((float4*)XS)[t] = v;
    float sq = v.x*v.x + v.y*v.y + v.z*v.z + v.w*v.w;
#pragma unroll
    for (int d = 32; d >= 1; d >>= 1) sq += __shfl_xor(sq, d);
    if (q == 0) denom[i] = sqrtf(sq) + 1e-6f;
  }
  __syncthreads();

  const int j = t & 255, ks = t >> 8;
  const int kb = ks * 64;
  { // layer 1: 4 batches of 16 loads
    const float* Wc = W1 + (size_t)n * EDIM * EDIM + (size_t)kb * EDIM + j;
    float a[8] = {0.f,0.f,0.f,0.f,0.f,0.f,0.f,0.f};
#pragma unroll 1
    for (int kk = 0; kk < 64; kk += 16) {
      float wv[16];
#pragma unroll
      for (int u = 0; u < 16; u++) wv[u] = Wc[(size_t)(kk + u) * EDIM];
#pragma unroll
      for (int u4 = 0; u4 < 16; u4 += 4) {
        const int k = kb + kk + u4;
#pragma unroll
        for (int i = 0; i < 8; i++) {
          const float4 s4 = *(const float4*)&XS[i * EDIM + k];
          a[i] = fmaf(s4.x, wv[u4+0], a[i]); a[i] = fmaf(s4.y, wv[u4+1], a[i]);
          a[i] = fmaf(s4.z, wv[u4+2], a[i]); a[i] = fmaf(s4.w, wv[u4+3], a[i]);
        }
      }
    }
#pragma unroll
    for (int q = 0; q < 8; q++) P[ks][j][q] = a[q];
  }
  __syncthreads();
  { const int j2 = t & 255, ih = t >> 8;
    const float bb = b1[(size_t)n * EDIM + j2];
#pragma unroll
    for (int qq = 0; qq < 2; qq++) {
      const int i = ih + qq * 4;
      float s = P[0][j2][i] + P[1][j2][i] + P[2][j2][i] + P[3][j2][i] + bb;
      H[j2][i] = fmaxf(s, 0.f);
    }
  }
  __syncthreads();
  { // layer 2: 4 batches of 16 loads; FMA order (k asc, 8 rows per k)
    const float* Wc = W2 + (size_t)n * EDIM * EDIM + (size_t)kb * EDIM + j;
    float a[8] = {0.f,0.f,0.f,0.f,0.f,0.f,0.f,0.f};
#pragma unroll 1
    for (int kk = 0; kk < 64; kk += 16) {
      float wv[16];
#pragma unroll
      for (int u = 0; u < 16; u++) wv[u] = Wc[(size_t)(kk + u) * EDIM];
#pragma unroll
      for (int u = 0; u < 16; u++) {
        const int k = kb + kk + u;
        const float4 h0 = *(const float4*)&H[k][0];
        const float4 h1 = *(const float4*)&H[k][4];
        const float w = wv[u];
        a[0] = fmaf(h0.x, w, a[0]); a[1] = fmaf(h0.y, w, a[1]);
        a[2] = fmaf(h0.z, w, a[2]); a[3] = fmaf(h0.w, w, a[3]);
        a[4] = fmaf(h1.x, w, a[4]); a[5] = fmaf(h1.y, w, a[5]);
        a[6] = fmaf(h1.z, w, a[6]); a[7] = fmaf(h1.w, w, a[7]);
      }
    }
#pragma unroll
    for (int q = 0; q < 8; q++) P[ks][j][q] = a[q];
  }
  __syncthreads();
  { const int col = t & 255, ih = t >> 8;
    const float bb2 = b2[(size_t)n * EDIM + col];
#pragma unroll
    for (int qq = 0; qq < 2; qq++) {
      const int i = ih + qq * 4;
      if (i < m) {
        float s = P[0][col][i] + P[1][col][i] + P[2][col][i] + P[3][col][i] + bb2;
        const int row = rowsl[i] & 1023;
        state[(size_t)row * EDIM + col] = fmaxf(s, 0.f) / denom[i];
      }
    }
  }
}

// ============ B4 + head ============
__global__ __launch_bounds__(1024, 4) void k_block_final(
    const float* __restrict__ state,
    const float* __restrict__ W1, const float* __restrict__ b1,
    const float* __restrict__ W2, const float* __restrict__ b2,
    const float* __restrict__ initial,
    const float* __restrict__ oW1, const float* __restrict__ ob1,
    const float* __restrict__ oW2, const float* __restrict__ ob2,
    const int* __restrict__ nn4, float* __restrict__ out) {
  __shared__ float XS[8 * EDIM];
  __shared__ float P[4][EDIM][9];
  __shared__ float H[EDIM][12];
  __shared__ float P2[8][8][16];
  __shared__ int hist[64];
  __shared__ int meta[4];
  __shared__ int rowsl[8];
  __shared__ float denom[8];
  __shared__ int wcnt[16], wbase[16];
  const int t = threadIdx.x;
  const int c = ((blockIdx.x & 7) * 24) + (blockIdx.x >> 3);

  if (t < 64) hist[t] = 0;
  if (t < 8) rowsl[t] = 0;
  __syncthreads();
  int vmy = nn4[t];
  if (vmy < 0) vmy = 0;                 // exited rows re-enter at origin
  atomicAdd(&hist[vmy], 1);
  __syncthreads();
  if (t < 64) {
    const int cnt = hist[t];
    const int nch = (cnt + 7) >> 3;
    int icnt = cnt, inch = nch;
#pragma unroll
    for (int d = 1; d < 64; d <<= 1) {
      int t1 = __shfl_up(icnt, d), t2 = __shfl_up(inch, d);
      if (t >= d) { icnt += t1; inch += t2; }
    }
    const int ench = inch - nch;
    if (t == 63) meta[3] = inch;
    if (c >= ench && c < ench + nch) {
      meta[0] = t; meta[1] = c - ench;
      meta[2] = min(8, cnt - (c - ench) * 8);
    }
  }
  __syncthreads();
  if (c >= meta[3]) return;
  const int n = meta[0], local = meta[1], m = meta[2];

  { const bool flag = (vmy == n);
    const unsigned long long bal = __ballot(flag);
    const int wid = t >> 6, lane = t & 63;
    if (lane == 0) wcnt[wid] = __popcll(bal);
    __syncthreads();
    if (t == 0) { int s = 0; for (int w = 0; w < 16; w++) { wbase[w] = s; s += wcnt[w]; } }
    __syncthreads();
    if (flag) {
      const int rank = wbase[wid] + __popcll(bal & ((1ull << lane) - 1ull));
      const int r0 = local * 8;
      if (rank >= r0 && rank < r0 + 8) rowsl[rank - r0] = t;
    }
    __syncthreads();
  }

  if (t < 512) {
    const int i = t >> 6, q = t & 63;
    const int row = rowsl[min(i, m - 1)] & 1023;
    const float4 v = *(const float4*)(state + (size_t)row * EDIM + q * 4);
    ((float4*)XS)[t] = v;
    float sq = v.x*v.x + v.y*v.y + v.z*v.z + v.w*v.w;
#pragma unroll
    for (int d = 32; d >= 1; d >>= 1) sq += __shfl_xor(sq, d);
    if (q == 0) denom[i] = sqrtf(sq) + 1e-6f;
  }
  __syncthreads();

  const int j = t & 255, ks = t >> 8;
  const int kb = ks * 64;
  { const float* Wc = W1 + (size_t)n * EDIM * EDIM + (size_t)kb * EDIM + j;
    float a[8] = {0.f,0.f,0.f,0.f,0.f,0.f,0.f,0.f};
#pragma unroll 1
    for (int kk = 0; kk < 64; kk += 16) {
      float wv[16];
#pragma unroll
      for (int u = 0; u < 16; u++) wv[u] = Wc[(size_t)(kk + u) * EDIM];
#pragma unroll
      for (int u4 = 0; u4 < 16; u4 += 4) {
        const int k = kb + kk + u4;
#pragma unroll
        for (int i = 0; i < 8; i++) {
          const float4 s4 = *(const float4*)&XS[i * EDIM + k];
          a[i] = fmaf(s4.x, wv[u4+0], a[i]); a[i] = fmaf(s4.y, wv[u4+1], a[i]);
          a[i] = fmaf(s4.z, wv[u4+2], a[i]); a[i] = fmaf(s4.w, wv[u4+3], a[i]);
        }
      }
    }
#pragma unroll
    for (int q = 0; q < 8; q++) P[ks][j][q] = a[q];
  }
  __syncthreads();
  { const int j2 = t & 255, ih = t >> 8;
    const float bb = b1[(size_t)n * EDIM + j2];
#pragma unroll
    for (int qq = 0; qq < 2; qq++) {
      const int i = ih + qq * 4;
      float s = P[0][j2][i] + P[1][j2][i] + P[2][j2][i] + P[3][j2][i] + bb;
      H[j2][i] = fmaxf(s, 0.f);
    }
  }
  __syncthreads();
  { const float* Wc = W2 + (size_t)n * EDIM * EDIM + (size_t)kb * EDIM + j;
    float a[8] = {0.f,0.f,0.f,0.f,0.f,0.f,0.f,0.f};
#pragma unroll 1
    for (int kk = 0; kk < 64; kk += 16) {
      float wv[16];
#pragma unroll
      for (int u = 0; u < 16; u++) wv[u] = Wc[(size_t)(kk + u) * EDIM];
#pragma unroll
      for (int u = 0; u < 16; u++) {
        const int k = kb + kk + u;
        const float4 h0 = *(const float4*)&H[k][0];
        const float4 h1 = *(const float4*)&H[k][4];
        const float w = wv[u];
        a[0] = fmaf(h0.x, w, a[0]); a[1] = fmaf(h0.y, w, a[1]);
        a[2] = fmaf(h0.z, w, a[2]); a[3] = fmaf(h0.w, w, a[3]);
        a[4] = fmaf(h1.x, w, a[4]); a[5] = fmaf(h1.y, w, a[5]);
        a[6] = fmaf(h1.z, w, a[6]); a[7] = fmaf(h1.w, w, a[7]);
      }
    }
#pragma unroll
    for (int q = 0; q < 8; q++) P[ks][j][q] = a[q];
  }
  __syncthreads();
  { const int col = t & 255, ih = t >> 8;
    const float bb2 = b2[(size_t)n * EDIM + col];
#pragma unroll
    for (int qq = 0; qq < 2; qq++) {
      const int i = ih + qq * 4;
      if (i < m) {
        float s = P[0][col][i] + P[1][col][i] + P[2][col][i] + P[3][col][i] + bb2;
        float v = fmaxf(s, 0.f) / denom[i];
        const int row = rowsl[i] & 1023;
        v += initial[(size_t)row * EDIM + col];
        XS[i * EDIM + col] = v;          // head input
      }
    }
  }
  __syncthreads();

  // ---- head ----
  { const float* Wc = oW1 + (size_t)kb * EDIM + j;
    float a[8] = {0.f,0.f,0.f,0.f,0.f,0.f,0.f,0.f};
#pragma unroll 1
    for (int kk = 0; kk < 64; kk += 16) {
      float wv[16];
#pragma unroll
      for (int u = 0; u < 16; u++) wv[u] = Wc[(size_t)(kk + u) * EDIM];
#pragma unroll
      for (int u4 = 0; u4 < 16; u4 += 4) {
        const int k = kb + kk + u4;
#pragma unroll
        for (int i = 0; i < 8; i++) {
          const float4 s4 = *(const float4*)&XS[i * EDIM + k];
          a[i] = fmaf(s4.x, wv[u4+0], a[i]); a[i] = fmaf(s4.y, wv[u4+1], a[i]);
          a[i] = fmaf(s4.z, wv[u4+2], a[i]); a[i] = fmaf(s4.w, wv[u4+3], a[i]);
        }
      }
    }
#pragma unroll
    for (int q = 0; q < 8; q++) P[ks][j][q] = a[q];
  }
  __syncthreads();
  { const int j2 = t & 255, ih = t >> 8;
    const float bb = ob1[j2];
#pragma unroll
    for (int qq = 0; qq < 2; qq++) {
      const int i = ih + qq * 4;
      float s = P[0][j2][i] + P[1][j2][i] + P[2][j2][i] + P[3][j2][i] + bb;
      H[j2][i] = fmaxf(s, 0.f);
    }
  }
  __syncthreads();
  { const int cc = t & 15, i = (t >> 4) & 7, ksl = t >> 7;   // 8 slices of 32
    float a2 = 0.f;
    if (cc < 10) {
      const int k0 = ksl * 32;
#pragma unroll 4
      for (int k = k0; k < k0 + 32; k++)
        a2 = fmaf(H[k][i], oW2[k * 10 + cc], a2);
    }
    P2[ksl][i][cc] = a2;
  }
  __syncthreads();
  if (t < 80) {
    const int i = t / 10, cc = t % 10;
    if (i < m) {
      float s = 0.f;
#pragma unroll
      for (int w = 0; w < 8; w++) s += P2[w][i][cc];
      const int row = rowsl[i] & 1023;
      out[(size_t)row * 10 + cc] = s + ob2[cc];
    }
  }
}

// ---------------- launch: 10 dispatches ----------------
extern "C" void kernel_launch(void* const* d_in, const int* in_sizes, int n_in,
                              void* d_out, int out_size, void* d_ws, size_t ws_size,
                              hipStream_t stream) {
  const float* x    = (const float*)d_in[0];
  const float* Wemb = (const float*)d_in[1];
  const float* bemb = (const float*)d_in[2];
  const float* stW1 = (const float*)d_in[3];
  const float* stb1 = (const float*)d_in[4];
  const float* stW2 = (const float*)d_in[5];
  const float* stb2 = (const float*)d_in[6];
  const float* aW1  = (const float*)d_in[7];
  const float* ab1  = (const float*)d_in[8];
  const float* aW2  = (const float*)d_in[9];
  const float* ab2  = (const float*)d_in[10];
  const float* oW1  = (const float*)d_in[11];
  const float* ob1  = (const float*)d_in[12];
  const float* oW2  = (const float*)d_in[13];
  const float* ob2  = (const float*)d_in[14];
  float* out = (float*)d_out;

  char* ws = (char*)d_ws;
  auto alloc = [&](size_t bytes) { char* p = ws; ws += (bytes + 255) & ~(size_t)255; return p; };
  float* state   = (float*)alloc((size_t)BATCH * EDIM * 4);
  float* initial = (float*)alloc((size_t)BATCH * EDIM * 4);
  int*   nn_all  = (int*)alloc(5 * BATCH * 4);

  k_embed_a0<<<BATCH / 4, 1024, 0, stream>>>(x, Wemb, bemb, aW1, ab1, aW2, ab2,
                                             state, initial, nn_all);
  for (int j = 0; j < 4; j++) {
    k_blocks<<<GRID_B, 1024, 0, stream>>>(state, stW1, stb1, stW2, stb2,
                                          nn_all + j * BATCH);
    k_addr<<<BATCH / 4, 1024, 0, stream>>>(state, aW1, ab1, aW2, ab2,
                                           nn_all + j * BATCH,
                                           nn_all + (j + 1) * BATCH, j + 1);
  }
  k_block_final<<<GRID_B, 1024, 0, stream>>>(state, stW1, stb1, stW2, stb2,
                                             initial, oW1, ob1, oW2, ob2,
                                             nn_all + 4 * BATCH, out);
}

// Round 8
// 255.198 us; speedup vs baseline: 1.3206x; 1.0996x over previous
//
#include <hip/hip_runtime.h>
#include <stdint.h>

// SelfOrganizingBrain: B=1024, IN=784, E=256, NCLS=10, N=64 blocks, NJUMPS=4.
// R7: LDS-pipe fix. R6 analysis: GEMM loops were LDS-throughput-bound
// (C=1 col/thread -> 4 FMA per ds_read_b128 broadcast; 49k cyc/CU of LDS
// vs 3.4k VALU -> VALUBusy 14%). R7 register-tiles 4 cols/thread
// (acc[4][4], ratio 16 FMA/read), 256-thread WGs, 4-row chunks, grid 304.
// K-slice boundaries + FMA order bit-identical to R6 -> absmax must stay
// exactly 1.2207e-3. 10 dispatches, in-place state, LDS-only atomics.

#define BATCH 1024
#define EDIM  256
#define INDIM 784
#define CH    4      // rows per chunk
#define GRID_B 304   // sum ceil(cnt_n/4) <= (1024 + 64*3)/4 = 304

// ---------------- threefry2x32 (exact JAX semantics, validated R0-R6) ----------------
__host__ __device__ inline uint32_t rotl32(uint32_t x, uint32_t d) {
  return (x << d) | (x >> (32u - d));
}
__host__ __device__ inline void threefry2x32(uint32_t k0, uint32_t k1,
                                             uint32_t x0, uint32_t x1,
                                             uint32_t* o0, uint32_t* o1) {
  uint32_t ks2 = k0 ^ k1 ^ 0x1BD11BDAu;
  x0 += k0; x1 += k1;
#define TF_R(a) { x0 += x1; x1 = rotl32(x1, a); x1 ^= x0; }
  TF_R(13) TF_R(15) TF_R(26) TF_R(6)   x0 += k1;  x1 += ks2 + 1u;
  TF_R(17) TF_R(29) TF_R(16) TF_R(24)  x0 += ks2; x1 += k0  + 2u;
  TF_R(13) TF_R(15) TF_R(26) TF_R(6)   x0 += k0;  x1 += k1  + 3u;
  TF_R(17) TF_R(29) TF_R(16) TF_R(24)  x0 += k1;  x1 += ks2 + 4u;
  TF_R(13) TF_R(15) TF_R(26) TF_R(6)   x0 += ks2; x1 += k0  + 5u;
#undef TF_R
  *o0 = x0; *o1 = x1;
}
__device__ inline uint32_t jax_bits12288(uint32_t k0, uint32_t k1, uint32_t L) {
  uint32_t o0, o1;
  if (L < 6144u) { threefry2x32(k0, k1, L, L + 6144u, &o0, &o1); return o0; }
  else           { threefry2x32(k0, k1, L - 6144u, L, &o0, &o1); return o1; }
}
__device__ inline float jax_uniform(uint32_t bits) {
  const float minv = 1e-6f;
  const float maxv = (float)(1.0 - 1e-06);
  const float span = maxv - minv;
  uint32_t fb = (bits >> 9) | 0x3f800000u;
  float f = __uint_as_float(fb) - 1.0f;
  float u = __fadd_rn(__fmul_rn(f, span), minv);
  return fmaxf(minv, u);
}
__device__ inline float gumbel_val(int s, int b, int c) {
  uint32_t fk0, fk1;
  threefry2x32(0u, 42u, 0u, (uint32_t)s, &fk0, &fk1);   // fold_in(key(42), s)
  const uint32_t L = (uint32_t)(b * 12 + c);
  const float u = jax_uniform(jax_bits12288(fk0, fk1, L));
  return -logf(-logf(u));
}
__device__ inline int addr_argmax(const float* v) {
  int i0 = 0, i1 = 0, i2 = 0;
  { float b = v[0];
    for (int c = 1; c < 4; c++) { float x = v[c];     if (x > b) { b = x; i0 = c; } } }
  { float b = v[4];
    for (int c = 1; c < 4; c++) { float x = v[4 + c]; if (x > b) { b = x; i1 = c; } } }
  { float b = v[8];
    for (int c = 1; c < 4; c++) { float x = v[8 + c]; if (x > b) { b = x; i2 = c; } } }
  return i0 * 16 + i1 * 4 + i2;
}

// ---- register-tiled layer: acc[4 rows][4 cols], src rows in LDS (stride SROW),
//      weights streamed from global. FMA order: k ascending per accumulator
//      (bit-identical to R6's per-(i,col) order). KS must be multiple of 4. ----
#define GEMM_TILE(Wbase, XSarr, SROW, kb, KS, acc)                              \
  {                                                                             \
    const float* Wc = (Wbase) + (size_t)(kb) * EDIM + jc;                       \
    _Pragma("unroll 1")                                                         \
    for (int kk = 0; kk < (KS); kk += 4) {                                      \
      float wv[16];                                                             \
      _Pragma("unroll")                                                         \
      for (int q = 0; q < 4; q++) {                                             \
        _Pragma("unroll")                                                       \
        for (int cc = 0; cc < 4; cc++)                                          \
          wv[q * 4 + cc] = Wc[(size_t)(kk + q) * EDIM + cc * 64];               \
      }                                                                         \
      const int k = (kb) + kk;                                                  \
      const float4 r0 = *(const float4*)&(XSarr)[0 * (SROW) + k];               \
      const float4 r1 = *(const float4*)&(XSarr)[1 * (SROW) + k];               \
      const float4 r2 = *(const float4*)&(XSarr)[2 * (SROW) + k];               \
      const float4 r3 = *(const float4*)&(XSarr)[3 * (SROW) + k];               \
      _Pragma("unroll")                                                         \
      for (int cc = 0; cc < 4; cc++) {                                          \
        acc[0][cc] = fmaf(r0.x, wv[0 + cc], acc[0][cc]);                        \
        acc[0][cc] = fmaf(r0.y, wv[4 + cc], acc[0][cc]);                        \
        acc[0][cc] = fmaf(r0.z, wv[8 + cc], acc[0][cc]);                        \
        acc[0][cc] = fmaf(r0.w, wv[12 + cc], acc[0][cc]);                       \
        acc[1][cc] = fmaf(r1.x, wv[0 + cc], acc[1][cc]);                        \
        acc[1][cc] = fmaf(r1.y, wv[4 + cc], acc[1][cc]);                        \
        acc[1][cc] = fmaf(r1.z, wv[8 + cc], acc[1][cc]);                        \
        acc[1][cc] = fmaf(r1.w, wv[12 + cc], acc[1][cc]);                       \
        acc[2][cc] = fmaf(r2.x, wv[0 + cc], acc[2][cc]);                        \
        acc[2][cc] = fmaf(r2.y, wv[4 + cc], acc[2][cc]);                        \
        acc[2][cc] = fmaf(r2.z, wv[8 + cc], acc[2][cc]);                        \
        acc[2][cc] = fmaf(r2.w, wv[12 + cc], acc[2][cc]);                       \
        acc[3][cc] = fmaf(r3.x, wv[0 + cc], acc[3][cc]);                        \
        acc[3][cc] = fmaf(r3.y, wv[4 + cc], acc[3][cc]);                        \
        acc[3][cc] = fmaf(r3.z, wv[8 + cc], acc[3][cc]);                        \
        acc[3][cc] = fmaf(r3.w, wv[12 + cc], acc[3][cc]);                       \
      }                                                                         \
    }                                                                           \
  }

// write acc -> P[kg][col][4]; P flat [4][256][4]
#define P_STORE(P, kg, jc, acc)                                                 \
  { _Pragma("unroll")                                                           \
    for (int cc = 0; cc < 4; cc++) {                                            \
      const int col = (jc) + cc * 64;                                           \
      *(float4*)&(P)[(((kg) * 256) + col) * 4] =                                \
        make_float4(acc[0][cc], acc[1][cc], acc[2][cc], acc[3][cc]);            \
    } }

// layer-2 tile (H[k][0..3] per k): acc order bit-identical to R6 layer2
#define GEMM_TILE_H(Wbase, Harr, kb, KS, acc)                                   \
  {                                                                             \
    const float* Wc = (Wbase) + (size_t)(kb) * EDIM + jc;                       \
    _Pragma("unroll 1")                                                         \
    for (int kk = 0; kk < (KS); kk += 4) {                                      \
      float wv[16];                                                             \
      _Pragma("unroll")                                                         \
      for (int q = 0; q < 4; q++) {                                             \
        _Pragma("unroll")                                                       \
        for (int cc = 0; cc < 4; cc++)                                          \
          wv[q * 4 + cc] = Wc[(size_t)(kk + q) * EDIM + cc * 64];               \
      }                                                                         \
      _Pragma("unroll")                                                         \
      for (int q = 0; q < 4; q++) {                                             \
        const float4 h = *(const float4*)&(Harr)[((kb) + kk + q) * 4];          \
        _Pragma("unroll")                                                       \
        for (int cc = 0; cc < 4; cc++) {                                        \
          acc[0][cc] = fmaf(h.x, wv[q * 4 + cc], acc[0][cc]);                   \
          acc[1][cc] = fmaf(h.y, wv[q * 4 + cc], acc[1][cc]);                   \
          acc[2][cc] = fmaf(h.z, wv[q * 4 + cc], acc[2][cc]);                   \
          acc[3][cc] = fmaf(h.w, wv[q * 4 + cc], acc[3][cc]);                   \
        }                                                                       \
      }                                                                         \
    }                                                                           \
  }

// ---- A-step tail: layer1 partials already in P; computes H, logits, vals.
// Bit-identical slicing to R6: H reduce over 4 kg; logits 16 slices of 16. ----
#define ADDR_TAIL(P, H, P2a, vals, ab1, aW2, ab2, astep, b0)                    \
  {                                                                             \
    { const int col = t;                                                        \
      float4 p0 = *(const float4*)&(P)[((0 * 256) + col) * 4];                  \
      float4 p1 = *(const float4*)&(P)[((1 * 256) + col) * 4];                  \
      float4 p2 = *(const float4*)&(P)[((2 * 256) + col) * 4];                  \
      float4 p3 = *(const float4*)&(P)[((3 * 256) + col) * 4];                  \
      const float bb = (ab1)[col];                                              \
      *(float4*)&(H)[col * 4] = make_float4(                                    \
        fmaxf(p0.x + p1.x + p2.x + p3.x + bb, 0.f),                             \
        fmaxf(p0.y + p1.y + p2.y + p3.y + bb, 0.f),                             \
        fmaxf(p0.z + p1.z + p2.z + p3.z + bb, 0.f),                             \
        fmaxf(p0.w + p1.w + p2.w + p3.w + bb, 0.f));                            \
    }                                                                           \
    __syncthreads();                                                            \
    { const int c = t & 15, ksl = t >> 4;                                       \
      float a2[4] = {0.f, 0.f, 0.f, 0.f};                                       \
      if (c < 12) {                                                             \
        const int k0 = ksl * 16;                                                \
        _Pragma("unroll 4")                                                     \
        for (int k = k0; k < k0 + 16; k++) {                                    \
          const float4 h = *(const float4*)&(H)[k * 4];                         \
          const float w = (aW2)[k * 12 + c];                                    \
          a2[0] = fmaf(h.x, w, a2[0]); a2[1] = fmaf(h.y, w, a2[1]);             \
          a2[2] = fmaf(h.z, w, a2[2]); a2[3] = fmaf(h.w, w, a2[3]);             \
        }                                                                       \
      }                                                                         \
      *(float4*)&(P2a)[(ksl * 16 + c) * 4] = make_float4(a2[0], a2[1], a2[2], a2[3]); \
    }                                                                           \
    __syncthreads();                                                            \
    if (t < 48) {                                                               \
      const int i = t / 12, c = t % 12;                                         \
      float s = 0.f;                                                            \
      _Pragma("unroll")                                                         \
      for (int w = 0; w < 16; w++) s += (P2a)[(w * 16 + c) * 4 + i];            \
      (vals)[i * 12 + c] = s + (ab2)[c] + gumbel_val((astep), (b0) + i, c);     \
    }                                                                           \
    __syncthreads();                                                            \
  }

// ============ E + A0: embed 4 rows/WG (grid 256) + addr step 0 ============
__global__ __launch_bounds__(256, 4) void k_embed_a0(
    const float* __restrict__ x, const float* __restrict__ Wemb,
    const float* __restrict__ bemb,
    const float* __restrict__ aW1, const float* __restrict__ ab1,
    const float* __restrict__ aW2, const float* __restrict__ ab2,
    float* __restrict__ state, float* __restrict__ initial,
    int* __restrict__ nn_all) {
  __shared__ __align__(16) float XS[4 * INDIM];   // 12.5 KB
  __shared__ __align__(16) float P[4 * 256 * 4];  // 16 KB
  __shared__ __align__(16) float SS[4 * EDIM];    // 4 KB
  __shared__ __align__(16) float H[EDIM * 4];     // 4 KB
  __shared__ __align__(16) float P2a[16 * 16 * 4];// 4 KB
  __shared__ float vals[4 * 12];
  const int t = threadIdx.x, b0 = blockIdx.x * 4;
  const int jc = t & 63, kg = t >> 6;

  { const float4* src = (const float4*)(x + (size_t)b0 * INDIM);
    for (int p = t; p < INDIM; p += 256) ((float4*)XS)[p] = src[p];
  }
  __syncthreads();

  { // embed layer: 4 K-slices of 196 (bit-identical boundaries to R6)
    const int kb = kg * 196;
    float acc[4][4] = {};
    GEMM_TILE(Wemb, XS, INDIM, kb, 196, acc);
    P_STORE(P, kg, jc, acc);
  }
  __syncthreads();
  { // reduce + bias -> SS + state + initial
    const int col = t;
    float4 p0 = *(const float4*)&P[((0 * 256) + col) * 4];
    float4 p1 = *(const float4*)&P[((1 * 256) + col) * 4];
    float4 p2 = *(const float4*)&P[((2 * 256) + col) * 4];
    float4 p3 = *(const float4*)&P[((3 * 256) + col) * 4];
    const float bb = bemb[col];
    float s0 = p0.x + p1.x + p2.x + p3.x + bb;
    float s1 = p0.y + p1.y + p2.y + p3.y + bb;
    float s2 = p0.z + p1.z + p2.z + p3.z + bb;
    float s3 = p0.w + p1.w + p2.w + p3.w + bb;
    SS[0 * EDIM + col] = s0; SS[1 * EDIM + col] = s1;
    SS[2 * EDIM + col] = s2; SS[3 * EDIM + col] = s3;
    state[(size_t)(b0 + 0) * EDIM + col] = s0; initial[(size_t)(b0 + 0) * EDIM + col] = s0;
    state[(size_t)(b0 + 1) * EDIM + col] = s1; initial[(size_t)(b0 + 1) * EDIM + col] = s1;
    state[(size_t)(b0 + 2) * EDIM + col] = s2; initial[(size_t)(b0 + 2) * EDIM + col] = s2;
    state[(size_t)(b0 + 3) * EDIM + col] = s3; initial[(size_t)(b0 + 3) * EDIM + col] = s3;
  }
  __syncthreads();

  { // A0 layer1 on SS: 4 K-slices of 64
    const int kb = kg * 64;
    float acc[4][4] = {};
    GEMM_TILE(aW1, SS, EDIM, kb, 64, acc);
    P_STORE(P, kg, jc, acc);
  }
  __syncthreads();
  ADDR_TAIL(P, H, P2a, vals, ab1, aW2, ab2, 0, b0);
  if (t < 4) nn_all[b0 + t] = addr_argmax(&vals[t * 12]);   // step 0: no exits
}

// ============ A_s (s=1..4): addr MLP, 4 rows/WG (grid 256) ============
__global__ __launch_bounds__(256, 4) void k_addr(
    const float* __restrict__ state,
    const float* __restrict__ aW1, const float* __restrict__ ab1,
    const float* __restrict__ aW2, const float* __restrict__ ab2,
    const int* __restrict__ nn_prev, int* __restrict__ nn_out, int step) {
  __shared__ __align__(16) float XS[4 * EDIM];
  __shared__ __align__(16) float P[4 * 256 * 4];
  __shared__ __align__(16) float H[EDIM * 4];
  __shared__ __align__(16) float P2a[16 * 16 * 4];
  __shared__ float vals[4 * 12];
  const int t = threadIdx.x, b0 = blockIdx.x * 4;
  const int jc = t & 63, kg = t >> 6;

  ((float4*)XS)[t] = ((const float4*)(state + (size_t)b0 * EDIM))[t];
  __syncthreads();

  { const int kb = kg * 64;
    float acc[4][4] = {};
    GEMM_TILE(aW1, XS, EDIM, kb, 64, acc);
    P_STORE(P, kg, jc, acc);
  }
  __syncthreads();
  ADDR_TAIL(P, H, P2a, vals, ab1, aW2, ab2, step, b0);
  if (t < 4) {
    const int b = b0 + t;
    int nxt;
    if (nn_prev[b] < 0) nxt = -1;
    else {
      const int nn = addr_argmax(&vals[t * 12]);
      nxt = (step < 4 && nn == 0) ? -1 : nn;
    }
    nn_out[b] = nxt;
  }
}

// ---- shared routing prologue for B kernels (256 threads, 4 rows/chunk) ----
// Produces: n, local, m, rowsl[4]; returns false if spare WG.
#define B_ROUTE(nnval_expr)                                                     \
  if (t < 64) hist[t] = 0;                                                      \
  if (t < 4) rowsl[t] = 0;                                                      \
  __syncthreads();                                                              \
  int myv[4]; bool fl[4];                                                       \
  _Pragma("unroll")                                                             \
  for (int p = 0; p < 4; p++) {                                                 \
    const int rr = p * 256 + t;                                                 \
    myv[p] = (nnval_expr);                                                      \
    if (myv[p] >= 0) atomicAdd(&hist[myv[p]], 1);                               \
  }                                                                             \
  __syncthreads();                                                              \
  if (t < 64) {                                                                 \
    const int cnt = hist[t];                                                    \
    const int nch = (cnt + CH - 1) / CH;                                        \
    int icnt = cnt, inch = nch;                                                 \
    _Pragma("unroll")                                                           \
    for (int d = 1; d < 64; d <<= 1) {                                          \
      int t1 = __shfl_up(icnt, d), t2 = __shfl_up(inch, d);                     \
      if (t >= d) { icnt += t1; inch += t2; }                                   \
    }                                                                           \
    const int ench = inch - nch;                                                \
    if (t == 63) meta[3] = inch;                                                \
    if (c >= ench && c < ench + nch) {                                          \
      meta[0] = t; meta[1] = c - ench;                                          \
      meta[2] = min(CH, cnt - (c - ench) * CH);                                 \
    }                                                                           \
  }                                                                             \
  __syncthreads();                                                              \
  if (c >= meta[3]) return;                                                     \
  const int n = meta[0], local = meta[1], m = meta[2];                          \
  {                                                                             \
    const int wid = t >> 6, lane = t & 63;                                      \
    unsigned long long bals[4];                                                 \
    _Pragma("unroll")                                                           \
    for (int p = 0; p < 4; p++) {                                               \
      fl[p] = (myv[p] == n);                                                    \
      bals[p] = __ballot(fl[p]);                                                \
      if (lane == 0) wcnt2[p * 4 + wid] = __popcll(bals[p]);                    \
    }                                                                           \
    __syncthreads();                                                            \
    if (t == 0) { int s = 0;                                                    \
      for (int e = 0; e < 16; e++) { wbase2[e] = s; s += wcnt2[e]; } }          \
    __syncthreads();                                                            \
    const int r0 = local * CH;                                                  \
    _Pragma("unroll")                                                           \
    for (int p = 0; p < 4; p++) {                                               \
      if (fl[p]) {                                                              \
        const int rank = wbase2[p * 4 + wid] +                                  \
          __popcll(bals[p] & ((1ull << lane) - 1ull));                          \
        if (rank >= r0 && rank < r0 + CH) rowsl[rank - r0] = p * 256 + t;       \
      }                                                                         \
    }                                                                           \
    __syncthreads();                                                            \
  }

// ============ B_j: routed block eval in-place (grid 304, 256 thr) ============
__global__ __launch_bounds__(256, 4) void k_blocks(
    float* __restrict__ state,
    const float* __restrict__ W1, const float* __restrict__ b1,
    const float* __restrict__ W2, const float* __restrict__ b2,
    const int* __restrict__ nnj) {
  __shared__ __align__(16) float XS[4 * EDIM];
  __shared__ __align__(16) float P[4 * 256 * 4];
  __shared__ __align__(16) float H[EDIM * 4];
  __shared__ int hist[64], meta[4], rowsl[4];
  __shared__ int wcnt2[16], wbase2[16];
  __shared__ float denom[4];
  const int t = threadIdx.x;
  const int c = ((blockIdx.x & 7) * 38) + (blockIdx.x >> 3);   // XCD swizzle (304=8*38)
  const int jc = t & 63, kg = t >> 6;

  B_ROUTE(nnj[rr])

  { // stage 4 rows (wave i <-> row i) + norms
    const int i = t >> 6, q = t & 63;
    const int row = rowsl[min(i, m - 1)] & 1023;
    const float4 v = *(const float4*)(state + (size_t)row * EDIM + q * 4);
    ((float4*)XS)[t] = v;
    float sq = v.x * v.x + v.y * v.y + v.z * v.z + v.w * v.w;
#pragma unroll
    for (int d = 32; d >= 1; d >>= 1) sq += __shfl_xor(sq, d);
    if (q == 0) denom[i] = sqrtf(sq) + 1e-6f;
  }
  __syncthreads();

  const float* W1n = W1 + (size_t)n * EDIM * EDIM;
  const float* W2n = W2 + (size_t)n * EDIM * EDIM;
  const int kb = kg * 64;
  { float acc[4][4] = {};
    GEMM_TILE(W1n, XS, EDIM, kb, 64, acc);
    P_STORE(P, kg, jc, acc);
  }
  __syncthreads();
  { // H reduce (bit-identical to R6: 4 kg ascending)
    const int col = t;
    float4 p0 = *(const float4*)&P[((0 * 256) + col) * 4];
    float4 p1 = *(const float4*)&P[((1 * 256) + col) * 4];
    float4 p2 = *(const float4*)&P[((2 * 256) + col) * 4];
    float4 p3 = *(const float4*)&P[((3 * 256) + col) * 4];
    const float bb = b1[(size_t)n * EDIM + col];
    *(float4*)&H[col * 4] = make_float4(
      fmaxf(p0.x + p1.x + p2.x + p3.x + bb, 0.f),
      fmaxf(p0.y + p1.y + p2.y + p3.y + bb, 0.f),
      fmaxf(p0.z + p1.z + p2.z + p3.z + bb, 0.f),
      fmaxf(p0.w + p1.w + p2.w + p3.w + bb, 0.f));
  }
  __syncthreads();
  { float acc[4][4] = {};
    GEMM_TILE_H(W2n, H, kb, 64, acc);
    P_STORE(P, kg, jc, acc);
  }
  __syncthreads();
  { // epilogue: relu/denom -> state (in-place)
    const int col = t;
    float4 p0 = *(const float4*)&P[((0 * 256) + col) * 4];
    float4 p1 = *(const float4*)&P[((1 * 256) + col) * 4];
    float4 p2 = *(const float4*)&P[((2 * 256) + col) * 4];
    float4 p3 = *(const float4*)&P[((3 * 256) + col) * 4];
    const float bb = b2[(size_t)n * EDIM + col];
    float s[4] = { p0.x + p1.x + p2.x + p3.x + bb,
                   p0.y + p1.y + p2.y + p3.y + bb,
                   p0.z + p1.z + p2.z + p3.z + bb,
                   p0.w + p1.w + p2.w + p3.w + bb };
#pragma unroll
    for (int i = 0; i < 4; i++) {
      if (i < m) {
        const int row = rowsl[i] & 1023;
        state[(size_t)row * EDIM + col] = fmaxf(s[i], 0.f) / denom[i];
      }
    }
  }
}

// ============ B4 + head (grid 304, 256 thr) ============
__global__ __launch_bounds__(256, 4) void k_block_final(
    const float* __restrict__ state,
    const float* __restrict__ W1, const float* __restrict__ b1,
    const float* __restrict__ W2, const float* __restrict__ b2,
    const float* __restrict__ initial,
    const float* __restrict__ oW1, const float* __restrict__ ob1,
    const float* __restrict__ oW2, const float* __restrict__ ob2,
    const int* __restrict__ nn4, float* __restrict__ out) {
  __shared__ __align__(16) float XS[4 * EDIM];
  __shared__ __align__(16) float P[4 * 256 * 4];
  __shared__ __align__(16) float H[EDIM * 4];
  __shared__ __align__(16) float P2h[8 * 16 * 4];   // 2 KB
  __shared__ int hist[64], meta[4], rowsl[4];
  __shared__ int wcnt2[16], wbase2[16];
  __shared__ float denom[4];
  const int t = threadIdx.x;
  const int c = ((blockIdx.x & 7) * 38) + (blockIdx.x >> 3);
  const int jc = t & 63, kg = t >> 6;

  B_ROUTE(max(nn4[rr], 0))   // exited rows re-enter at origin

  { const int i = t >> 6, q = t & 63;
    const int row = rowsl[min(i, m - 1)] & 1023;
    const float4 v = *(const float4*)(state + (size_t)row * EDIM + q * 4);
    ((float4*)XS)[t] = v;
    float sq = v.x * v.x + v.y * v.y + v.z * v.z + v.w * v.w;
#pragma unroll
    for (int d = 32; d >= 1; d >>= 1) sq += __shfl_xor(sq, d);
    if (q == 0) denom[i] = sqrtf(sq) + 1e-6f;
  }
  __syncthreads();

  const float* W1n = W1 + (size_t)n * EDIM * EDIM;
  const float* W2n = W2 + (size_t)n * EDIM * EDIM;
  const int kb = kg * 64;
  { float acc[4][4] = {};
    GEMM_TILE(W1n, XS, EDIM, kb, 64, acc);
    P_STORE(P, kg, jc, acc);
  }
  __syncthreads();
  { const int col = t;
    float4 p0 = *(const float4*)&P[((0 * 256) + col) * 4];
    float4 p1 = *(const float4*)&P[((1 * 256) + col) * 4];
    float4 p2 = *(const float4*)&P[((2 * 256) + col) * 4];
    float4 p3 = *(const float4*)&P[((3 * 256) + col) * 4];
    const float bb = b1[(size_t)n * EDIM + col];
    *(float4*)&H[col * 4] = make_float4(
      fmaxf(p0.x + p1.x + p2.x + p3.x + bb, 0.f),
      fmaxf(p0.y + p1.y + p2.y + p3.y + bb, 0.f),
      fmaxf(p0.z + p1.z + p2.z + p3.z + bb, 0.f),
      fmaxf(p0.w + p1.w + p2.w + p3.w + bb, 0.f));
  }
  __syncthreads();
  { float acc[4][4] = {};
    GEMM_TILE_H(W2n, H, kb, 64, acc);
    P_STORE(P, kg, jc, acc);
  }
  __syncthreads();
  { // final_output = relu/denom + initial -> XS (head input)
    const int col = t;
    float4 p0 = *(const float4*)&P[((0 * 256) + col) * 4];
    float4 p1 = *(const float4*)&P[((1 * 256) + col) * 4];
    float4 p2 = *(const float4*)&P[((2 * 256) + col) * 4];
    float4 p3 = *(const float4*)&P[((3 * 256) + col) * 4];
    const float bb = b2[(size_t)n * EDIM + col];
    float s[4] = { p0.x + p1.x + p2.x + p3.x + bb,
                   p0.y + p1.y + p2.y + p3.y + bb,
                   p0.z + p1.z + p2.z + p3.z + bb,
                   p0.w + p1.w + p2.w + p3.w + bb };
#pragma unroll
    for (int i = 0; i < 4; i++) {
      const int row = rowsl[i] & 1023;
      float v = fmaxf(s[i], 0.f) / denom[i];
      v += initial[(size_t)row * EDIM + col];
      XS[i * EDIM + col] = v;      // dup rows for i>=m harmless (guard at out)
    }
  }
  __syncthreads();

  // ---- head layer 1 (oW1): 4 K-slices of 64 ----
  { float acc[4][4] = {};
    GEMM_TILE(oW1, XS, EDIM, kb, 64, acc);
    P_STORE(P, kg, jc, acc);
  }
  __syncthreads();
  { const int col = t;
    float4 p0 = *(const float4*)&P[((0 * 256) + col) * 4];
    float4 p1 = *(const float4*)&P[((1 * 256) + col) * 4];
    float4 p2 = *(const float4*)&P[((2 * 256) + col) * 4];
    float4 p3 = *(const float4*)&P[((3 * 256) + col) * 4];
    const float bb = ob1[col];
    *(float4*)&H[col * 4] = make_float4(
      fmaxf(p0.x + p1.x + p2.x + p3.x + bb, 0.f),
      fmaxf(p0.y + p1.y + p2.y + p3.y + bb, 0.f),
      fmaxf(p0.z + p1.z + p2.z + p3.z + bb, 0.f),
      fmaxf(p0.w + p1.w + p2.w + p3.w + bb, 0.f));
  }
  __syncthreads();
  { // head layer 2: 8 slices of 32 (bit-identical to R6)
    if (t < 128) {
      const int cc = t & 15, ksl = t >> 4;
      float a2[4] = {0.f, 0.f, 0.f, 0.f};
      if (cc < 10) {
        const int k0 = ksl * 32;
#pragma unroll 4
        for (int k = k0; k < k0 + 32; k++) {
          const float4 h = *(const float4*)&H[k * 4];
          const float w = oW2[k * 10 + cc];
          a2[0] = fmaf(h.x, w, a2[0]); a2[1] = fmaf(h.y, w, a2[1]);
          a2[2] = fmaf(h.z, w, a2[2]); a2[3] = fmaf(h.w, w, a2[3]);
        }
      }
      *(float4*)&P2h[(ksl * 16 + cc) * 4] = make_float4(a2[0], a2[1], a2[2], a2[3]);
    }
  }
  __syncthreads();
  if (t < 40) {
    const int i = t / 10, cc = t % 10;
    if (i < m) {
      float s = 0.f;
#pragma unroll
      for (int w = 0; w < 8; w++) s += P2h[(w * 16 + cc) * 4 + i];
      const int row = rowsl[i] & 1023;
      out[(size_t)row * 10 + cc] = s + ob2[cc];
    }
  }
}

// ---------------- launch: 10 dispatches ----------------
extern "C" void kernel_launch(void* const* d_in, const int* in_sizes, int n_in,
                              void* d_out, int out_size, void* d_ws, size_t ws_size,
                              hipStream_t stream) {
  const float* x    = (const float*)d_in[0];
  const float* Wemb = (const float*)d_in[1];
  const float* bemb = (const float*)d_in[2];
  const float* stW1 = (const float*)d_in[3];
  const float* stb1 = (const float*)d_in[4];
  const float* stW2 = (const float*)d_in[5];
  const float* stb2 = (const float*)d_in[6];
  const float* aW1  = (const float*)d_in[7];
  const float* ab1  = (const float*)d_in[8];
  const float* aW2  = (const float*)d_in[9];
  const float* ab2  = (const float*)d_in[10];
  const float* oW1  = (const float*)d_in[11];
  const float* ob1  = (const float*)d_in[12];
  const float* oW2  = (const float*)d_in[13];
  const float* ob2  = (const float*)d_in[14];
  float* out = (float*)d_out;

  char* ws = (char*)d_ws;
  auto alloc = [&](size_t bytes) { char* p = ws; ws += (bytes + 255) & ~(size_t)255; return p; };
  float* state   = (float*)alloc((size_t)BATCH * EDIM * 4);
  float* initial = (float*)alloc((size_t)BATCH * EDIM * 4);
  int*   nn_all  = (int*)alloc(5 * BATCH * 4);

  k_embed_a0<<<BATCH / 4, 256, 0, stream>>>(x, Wemb, bemb, aW1, ab1, aW2, ab2,
                                            state, initial, nn_all);
  for (int j = 0; j < 4; j++) {
    k_blocks<<<GRID_B, 256, 0, stream>>>(state, stW1, stb1, stW2, stb2,
                                         nn_all + j * BATCH);
    k_addr<<<BATCH / 4, 256, 0, stream>>>(state, aW1, ab1, aW2, ab2,
                                          nn_all + j * BATCH,
                                          nn_all + (j + 1) * BATCH, j + 1);
  }
  k_block_final<<<GRID_B, 256, 0, stream>>>(state, stW1, stb1, stW2, stb2,
                                            initial, oW1, ob1, oW2, ob2,
                                            nn_all + 4 * BATCH, out);
}

// Round 10
// 227.325 us; speedup vs baseline: 1.4825x; 1.1226x over previous
//
#include <hip/hip_runtime.h>
#include <stdint.h>

// SelfOrganizingBrain: B=1024, IN=784, E=256, NCLS=10, N=64 blocks, NJUMPS=4.
// R9 = R8 with the macro-shadowing bug fixed: P_REDUCE8 declared an inner
// `float4 s` shadowing the caller's `s` -> dst never assigned -> garbage
// states (absmax 0.173). Macro temps now `_ps` (unique). Structure unchanged:
// 512-thr WGs (8 waves), K-split 8x32, 4-col register tiling (16 FMA per
// ds_read_b128), 2-stage named weight double-buffer. 10 dispatches.

#define BATCH 1024
#define EDIM  256
#define INDIM 784
#define CH    4      // rows per chunk
#define GRID_B 304   // sum ceil(cnt_n/4) <= 256 + 48 = 304 (8*38)

// ---------------- threefry2x32 (exact JAX semantics, validated R0-R7) ----------------
__host__ __device__ inline uint32_t rotl32(uint32_t x, uint32_t d) {
  return (x << d) | (x >> (32u - d));
}
__host__ __device__ inline void threefry2x32(uint32_t k0, uint32_t k1,
                                             uint32_t x0, uint32_t x1,
                                             uint32_t* o0, uint32_t* o1) {
  uint32_t ks2 = k0 ^ k1 ^ 0x1BD11BDAu;
  x0 += k0; x1 += k1;
#define TF_R(a) { x0 += x1; x1 = rotl32(x1, a); x1 ^= x0; }
  TF_R(13) TF_R(15) TF_R(26) TF_R(6)   x0 += k1;  x1 += ks2 + 1u;
  TF_R(17) TF_R(29) TF_R(16) TF_R(24)  x0 += ks2; x1 += k0  + 2u;
  TF_R(13) TF_R(15) TF_R(26) TF_R(6)   x0 += k0;  x1 += k1  + 3u;
  TF_R(17) TF_R(29) TF_R(16) TF_R(24)  x0 += k1;  x1 += ks2 + 4u;
  TF_R(13) TF_R(15) TF_R(26) TF_R(6)   x0 += ks2; x1 += k0  + 5u;
#undef TF_R
  *o0 = x0; *o1 = x1;
}
__device__ inline uint32_t jax_bits12288(uint32_t k0, uint32_t k1, uint32_t L) {
  uint32_t o0, o1;
  if (L < 6144u) { threefry2x32(k0, k1, L, L + 6144u, &o0, &o1); return o0; }
  else           { threefry2x32(k0, k1, L - 6144u, L, &o0, &o1); return o1; }
}
__device__ inline float jax_uniform(uint32_t bits) {
  const float minv = 1e-6f;
  const float maxv = (float)(1.0 - 1e-06);
  const float span = maxv - minv;
  uint32_t fb = (bits >> 9) | 0x3f800000u;
  float f = __uint_as_float(fb) - 1.0f;
  float u = __fadd_rn(__fmul_rn(f, span), minv);
  return fmaxf(minv, u);
}
__device__ inline float gumbel_val(int s, int b, int c) {
  uint32_t fk0, fk1;
  threefry2x32(0u, 42u, 0u, (uint32_t)s, &fk0, &fk1);   // fold_in(key(42), s)
  const uint32_t L = (uint32_t)(b * 12 + c);
  const float u = jax_uniform(jax_bits12288(fk0, fk1, L));
  return -logf(-logf(u));
}
__device__ inline int addr_argmax(const float* v) {
  int i0 = 0, i1 = 0, i2 = 0;
  { float b = v[0];
    for (int c = 1; c < 4; c++) { float x = v[c];     if (x > b) { b = x; i0 = c; } } }
  { float b = v[4];
    for (int c = 1; c < 4; c++) { float x = v[4 + c]; if (x > b) { b = x; i1 = c; } } }
  { float b = v[8];
    for (int c = 1; c < 4; c++) { float x = v[8 + c]; if (x > b) { b = x; i2 = c; } } }
  return i0 * 16 + i1 * 4 + i2;
}

// ---- 16 coalesced weight loads (4 k x 4 cols), constant-indexed dest ----
#define LDW16(dst, Wc, kkq)                                                     \
  { _Pragma("unroll")                                                           \
    for (int _q = 0; _q < 4; _q++) {                                            \
      _Pragma("unroll")                                                         \
      for (int _cc = 0; _cc < 4; _cc++)                                         \
        dst[_q * 4 + _cc] = (Wc)[(size_t)((kkq) + _q) * EDIM + _cc * 64];       \
    } }

// ---- 64 FMA from one 16-weight batch; 4 LDS b128 broadcasts ----
#define FMA16(acc, wv, XSarr, SROW, kabs)                                       \
  { const float4 _r0 = *(const float4*)&(XSarr)[0 * (SROW) + (kabs)];           \
    const float4 _r1 = *(const float4*)&(XSarr)[1 * (SROW) + (kabs)];           \
    const float4 _r2 = *(const float4*)&(XSarr)[2 * (SROW) + (kabs)];           \
    const float4 _r3 = *(const float4*)&(XSarr)[3 * (SROW) + (kabs)];           \
    _Pragma("unroll")                                                           \
    for (int _cc = 0; _cc < 4; _cc++) {                                         \
      acc[0][_cc] = fmaf(_r0.x, wv[0 + _cc], acc[0][_cc]);                      \
      acc[0][_cc] = fmaf(_r0.y, wv[4 + _cc], acc[0][_cc]);                      \
      acc[0][_cc] = fmaf(_r0.z, wv[8 + _cc], acc[0][_cc]);                      \
      acc[0][_cc] = fmaf(_r0.w, wv[12 + _cc], acc[0][_cc]);                     \
      acc[1][_cc] = fmaf(_r1.x, wv[0 + _cc], acc[1][_cc]);                      \
      acc[1][_cc] = fmaf(_r1.y, wv[4 + _cc], acc[1][_cc]);                      \
      acc[1][_cc] = fmaf(_r1.z, wv[8 + _cc], acc[1][_cc]);                      \
      acc[1][_cc] = fmaf(_r1.w, wv[12 + _cc], acc[1][_cc]);                     \
      acc[2][_cc] = fmaf(_r2.x, wv[0 + _cc], acc[2][_cc]);                      \
      acc[2][_cc] = fmaf(_r2.y, wv[4 + _cc], acc[2][_cc]);                      \
      acc[2][_cc] = fmaf(_r2.z, wv[8 + _cc], acc[2][_cc]);                      \
      acc[2][_cc] = fmaf(_r2.w, wv[12 + _cc], acc[2][_cc]);                     \
      acc[3][_cc] = fmaf(_r3.x, wv[0 + _cc], acc[3][_cc]);                      \
      acc[3][_cc] = fmaf(_r3.y, wv[4 + _cc], acc[3][_cc]);                      \
      acc[3][_cc] = fmaf(_r3.z, wv[8 + _cc], acc[3][_cc]);                      \
      acc[3][_cc] = fmaf(_r3.w, wv[12 + _cc], acc[3][_cc]);                     \
    } }

// ---- register-tiled GEMM slice, 2-stage pipelined (KS multiple of 8) ----
#define GEMM_TILE(Wbase, XSarr, SROW, kb, KS, acc)                              \
  { const float* _Wc = (Wbase) + (size_t)(kb) * EDIM + jc;                      \
    float _wvA[16], _wvB[16];                                                   \
    LDW16(_wvA, _Wc, 0)                                                         \
    _Pragma("unroll 1")                                                         \
    for (int _kk = 0; _kk < (KS); _kk += 8) {                                   \
      LDW16(_wvB, _Wc, _kk + 4)                                                 \
      FMA16(acc, _wvA, XSarr, SROW, (kb) + _kk)                                 \
      if (_kk + 8 < (KS)) LDW16(_wvA, _Wc, _kk + 8)                             \
      FMA16(acc, _wvB, XSarr, SROW, (kb) + _kk + 4)                             \
    } }

// layer-2 variant: activations from H[k][0..3] (b128 broadcast per k)
#define FMA16H(acc, wv, Harr, kabs)                                             \
  { _Pragma("unroll")                                                           \
    for (int _q = 0; _q < 4; _q++) {                                            \
      const float4 _h = *(const float4*)&(Harr)[((kabs) + _q) * 4];             \
      _Pragma("unroll")                                                         \
      for (int _cc = 0; _cc < 4; _cc++) {                                       \
        acc[0][_cc] = fmaf(_h.x, wv[_q * 4 + _cc], acc[0][_cc]);                \
        acc[1][_cc] = fmaf(_h.y, wv[_q * 4 + _cc], acc[1][_cc]);                \
        acc[2][_cc] = fmaf(_h.z, wv[_q * 4 + _cc], acc[2][_cc]);                \
        acc[3][_cc] = fmaf(_h.w, wv[_q * 4 + _cc], acc[3][_cc]);                \
      } } }

#define GEMM_TILE_H(Wbase, Harr, kb, KS, acc)                                   \
  { const float* _Wc = (Wbase) + (size_t)(kb) * EDIM + jc;                      \
    float _wvA[16], _wvB[16];                                                   \
    LDW16(_wvA, _Wc, 0)                                                         \
    _Pragma("unroll 1")                                                         \
    for (int _kk = 0; _kk < (KS); _kk += 8) {                                   \
      LDW16(_wvB, _Wc, _kk + 4)                                                 \
      FMA16H(acc, _wvA, Harr, (kb) + _kk)                                       \
      if (_kk + 8 < (KS)) LDW16(_wvA, _Wc, _kk + 8)                             \
      FMA16H(acc, _wvB, Harr, (kb) + _kk + 4)                                   \
    } }

// write acc -> P[kg][col][4]
#define P_STORE(P, kg, jc, acc)                                                 \
  { _Pragma("unroll")                                                           \
    for (int _cc = 0; _cc < 4; _cc++) {                                         \
      const int _col = (jc) + _cc * 64;                                         \
      *(float4*)&(P)[(((kg) * 256) + _col) * 4] =                               \
        make_float4(acc[0][_cc], acc[1][_cc], acc[2][_cc], acc[3][_cc]);        \
    } }

// reduce 8 kg partials + bias for col -> dst4 (rows 0..3). UNIQUE temp names!
#define P_REDUCE8(P, col, bias, dst4)                                           \
  { float4 _ps = *(const float4*)&(P)[(col) * 4];                               \
    _Pragma("unroll")                                                           \
    for (int _pw = 1; _pw < 8; _pw++) {                                         \
      const float4 _pp = *(const float4*)&(P)[((_pw * 256) + (col)) * 4];       \
      _ps.x += _pp.x; _ps.y += _pp.y; _ps.z += _pp.z; _ps.w += _pp.w;           \
    }                                                                           \
    _ps.x += (bias); _ps.y += (bias); _ps.z += (bias); _ps.w += (bias);         \
    dst4 = _ps; }

// ---- addr tail (512 thr): H reduce, aW2 logits (32 slices of 8), gumbel ----
#define ADDR_TAIL(P, H, P2a, vals, ab1, aW2, ab2, astep, b0)                    \
  { if (t < 256) {                                                              \
      float4 s; P_REDUCE8(P, t, (ab1)[t], s);                                   \
      *(float4*)&(H)[t * 4] = make_float4(fmaxf(s.x, 0.f), fmaxf(s.y, 0.f),     \
                                          fmaxf(s.z, 0.f), fmaxf(s.w, 0.f));    \
    }                                                                           \
    __syncthreads();                                                            \
    { const int c = t & 15, ksl = t >> 4;                                       \
      float a2[4] = {0.f, 0.f, 0.f, 0.f};                                       \
      if (c < 12) {                                                             \
        const int k0 = ksl * 8;                                                 \
        _Pragma("unroll")                                                       \
        for (int k = k0; k < k0 + 8; k++) {                                     \
          const float4 h = *(const float4*)&(H)[k * 4];                         \
          const float w = (aW2)[k * 12 + c];                                    \
          a2[0] = fmaf(h.x, w, a2[0]); a2[1] = fmaf(h.y, w, a2[1]);             \
          a2[2] = fmaf(h.z, w, a2[2]); a2[3] = fmaf(h.w, w, a2[3]);             \
        }                                                                       \
      }                                                                         \
      *(float4*)&(P2a)[(ksl * 16 + c) * 4] = make_float4(a2[0], a2[1], a2[2], a2[3]); \
    }                                                                           \
    __syncthreads();                                                            \
    if (t < 48) {                                                               \
      const int i = t / 12, c = t % 12;                                         \
      float s = 0.f;                                                            \
      _Pragma("unroll")                                                         \
      for (int w = 0; w < 32; w++) s += (P2a)[(w * 16 + c) * 4 + i];            \
      (vals)[i * 12 + c] = s + (ab2)[c] + gumbel_val((astep), (b0) + i, c);     \
    }                                                                           \
    __syncthreads();                                                            \
  }

// ============ E + A0: embed 4 rows/WG (grid 256, 512 thr) + addr step 0 ============
__global__ __launch_bounds__(512, 2) void k_embed_a0(
    const float* __restrict__ x, const float* __restrict__ Wemb,
    const float* __restrict__ bemb,
    const float* __restrict__ aW1, const float* __restrict__ ab1,
    const float* __restrict__ aW2, const float* __restrict__ ab2,
    float* __restrict__ state, float* __restrict__ initial,
    int* __restrict__ nn_all) {
  __shared__ __align__(16) float XS[4 * INDIM];    // 12.5 KB
  __shared__ __align__(16) float P[8 * 256 * 4];   // 32 KB
  __shared__ __align__(16) float SS[4 * EDIM];     // 4 KB
  __shared__ __align__(16) float H[EDIM * 4];      // 4 KB
  __shared__ __align__(16) float P2a[32 * 16 * 4]; // 8 KB
  __shared__ float vals[4 * 12];
  const int t = threadIdx.x, b0 = blockIdx.x * 4;
  const int jc = t & 63, kg = t >> 6;

  { const float4* src = (const float4*)(x + (size_t)b0 * INDIM);
    for (int p = t; p < INDIM; p += 512) ((float4*)XS)[p] = src[p];
  }
  __syncthreads();

  { // embed: 8 K-slices [104,104,96,96,96,96,96,96]
    const int kb = (kg < 2) ? kg * 104 : 208 + (kg - 2) * 96;
    float acc[4][4] = {};
    if (kg < 2) { GEMM_TILE(Wemb, XS, INDIM, kb, 104, acc); }
    else        { GEMM_TILE(Wemb, XS, INDIM, kb, 96, acc); }
    P_STORE(P, kg, jc, acc);
  }
  __syncthreads();
  if (t < 256) { // reduce + bias -> SS + state + initial
    float4 s; P_REDUCE8(P, t, bemb[t], s);
    SS[0 * EDIM + t] = s.x; SS[1 * EDIM + t] = s.y;
    SS[2 * EDIM + t] = s.z; SS[3 * EDIM + t] = s.w;
    state[(size_t)(b0 + 0) * EDIM + t] = s.x; initial[(size_t)(b0 + 0) * EDIM + t] = s.x;
    state[(size_t)(b0 + 1) * EDIM + t] = s.y; initial[(size_t)(b0 + 1) * EDIM + t] = s.y;
    state[(size_t)(b0 + 2) * EDIM + t] = s.z; initial[(size_t)(b0 + 2) * EDIM + t] = s.z;
    state[(size_t)(b0 + 3) * EDIM + t] = s.w; initial[(size_t)(b0 + 3) * EDIM + t] = s.w;
  }
  __syncthreads();

  { // A0 layer1: 8 slices of 32
    const int kb = kg * 32;
    float acc[4][4] = {};
    GEMM_TILE(aW1, SS, EDIM, kb, 32, acc);
    P_STORE(P, kg, jc, acc);
  }
  __syncthreads();
  ADDR_TAIL(P, H, P2a, vals, ab1, aW2, ab2, 0, b0);
  if (t < 4) nn_all[b0 + t] = addr_argmax(&vals[t * 12]);   // step 0: no exits
}

// ============ A_s (s=1..4): addr MLP, 4 rows/WG (grid 256, 512 thr) ============
__global__ __launch_bounds__(512, 2) void k_addr(
    const float* __restrict__ state,
    const float* __restrict__ aW1, const float* __restrict__ ab1,
    const float* __restrict__ aW2, const float* __restrict__ ab2,
    const int* __restrict__ nn_prev, int* __restrict__ nn_out, int step) {
  __shared__ __align__(16) float XS[4 * EDIM];
  __shared__ __align__(16) float P[8 * 256 * 4];
  __shared__ __align__(16) float H[EDIM * 4];
  __shared__ __align__(16) float P2a[32 * 16 * 4];
  __shared__ float vals[4 * 12];
  const int t = threadIdx.x, b0 = blockIdx.x * 4;
  const int jc = t & 63, kg = t >> 6;

  if (t < 256) ((float4*)XS)[t] = ((const float4*)(state + (size_t)b0 * EDIM))[t];
  __syncthreads();

  { const int kb = kg * 32;
    float acc[4][4] = {};
    GEMM_TILE(aW1, XS, EDIM, kb, 32, acc);
    P_STORE(P, kg, jc, acc);
  }
  __syncthreads();
  ADDR_TAIL(P, H, P2a, vals, ab1, aW2, ab2, step, b0);
  if (t < 4) {
    const int b = b0 + t;
    int nxt;
    if (nn_prev[b] < 0) nxt = -1;
    else {
      const int nn = addr_argmax(&vals[t * 12]);
      nxt = (step < 4 && nn == 0) ? -1 : nn;
    }
    nn_out[b] = nxt;
  }
}

// ---- routing prologue for B kernels (512 threads, 4 rows/chunk) ----
#define B_ROUTE(nnval_expr)                                                     \
  if (t < 64) hist[t] = 0;                                                      \
  if (t < 4) rowsl[t] = 0;                                                      \
  __syncthreads();                                                              \
  int myv[2]; bool fl[2];                                                       \
  _Pragma("unroll")                                                             \
  for (int p = 0; p < 2; p++) {                                                 \
    const int rr = p * 512 + t;                                                 \
    myv[p] = (nnval_expr);                                                      \
    if (myv[p] >= 0) atomicAdd(&hist[myv[p]], 1);                               \
  }                                                                             \
  __syncthreads();                                                              \
  if (t < 64) {                                                                 \
    const int cnt = hist[t];                                                    \
    const int nch = (cnt + CH - 1) / CH;                                        \
    int icnt = cnt, inch = nch;                                                 \
    _Pragma("unroll")                                                           \
    for (int d = 1; d < 64; d <<= 1) {                                          \
      int t1 = __shfl_up(icnt, d), t2 = __shfl_up(inch, d);                     \
      if (t >= d) { icnt += t1; inch += t2; }                                   \
    }                                                                           \
    const int ench = inch - nch;                                                \
    if (t == 63) meta[3] = inch;                                                \
    if (c >= ench && c < ench + nch) {                                          \
      meta[0] = t; meta[1] = c - ench;                                          \
      meta[2] = min(CH, cnt - (c - ench) * CH);                                 \
    }                                                                           \
  }                                                                             \
  __syncthreads();                                                              \
  if (c >= meta[3]) return;                                                     \
  const int n = meta[0], local = meta[1], m = meta[2];                          \
  {                                                                             \
    const int wid = t >> 6, lane = t & 63;                                      \
    unsigned long long bals[2];                                                 \
    _Pragma("unroll")                                                           \
    for (int p = 0; p < 2; p++) {                                               \
      fl[p] = (myv[p] == n);                                                    \
      bals[p] = __ballot(fl[p]);                                                \
      if (lane == 0) wcnt2[p * 8 + wid] = __popcll(bals[p]);                    \
    }                                                                           \
    __syncthreads();                                                            \
    if (t == 0) { int s = 0;                                                    \
      for (int e = 0; e < 16; e++) { wbase2[e] = s; s += wcnt2[e]; } }          \
    __syncthreads();                                                            \
    const int r0 = local * CH;                                                  \
    _Pragma("unroll")                                                           \
    for (int p = 0; p < 2; p++) {                                               \
      if (fl[p]) {                                                              \
        const int rank = wbase2[p * 8 + wid] +                                  \
          __popcll(bals[p] & ((1ull << lane) - 1ull));                          \
        if (rank >= r0 && rank < r0 + CH) rowsl[rank - r0] = p * 512 + t;       \
      }                                                                         \
    }                                                                           \
    __syncthreads();                                                            \
  }

// ============ B_j: routed block eval in-place (grid 304, 512 thr) ============
__global__ __launch_bounds__(512, 2) void k_blocks(
    float* __restrict__ state,
    const float* __restrict__ W1, const float* __restrict__ b1,
    const float* __restrict__ W2, const float* __restrict__ b2,
    const int* __restrict__ nnj) {
  __shared__ __align__(16) float XS[4 * EDIM];
  __shared__ __align__(16) float P[8 * 256 * 4];
  __shared__ __align__(16) float H[EDIM * 4];
  __shared__ int hist[64], meta[4], rowsl[4];
  __shared__ int wcnt2[16], wbase2[16];
  __shared__ float denom[4];
  const int t = threadIdx.x;
  const int c = ((blockIdx.x & 7) * 38) + (blockIdx.x >> 3);   // XCD swizzle
  const int jc = t & 63, kg = t >> 6;

  B_ROUTE(nnj[rr])

  if (t < 256) { // stage 4 rows + norms (wave i <-> row i)
    const int i = t >> 6, q = t & 63;
    const int row = rowsl[min(i, m - 1)] & 1023;
    const float4 v = *(const float4*)(state + (size_t)row * EDIM + q * 4);
    ((float4*)XS)[t] = v;
    float sq = v.x * v.x + v.y * v.y + v.z * v.z + v.w * v.w;
#pragma unroll
    for (int d = 32; d >= 1; d >>= 1) sq += __shfl_xor(sq, d);
    if (q == 0) denom[i] = sqrtf(sq) + 1e-6f;
  }
  __syncthreads();

  const float* W1n = W1 + (size_t)n * EDIM * EDIM;
  const float* W2n = W2 + (size_t)n * EDIM * EDIM;
  const int kb = kg * 32;
  { float acc[4][4] = {};
    GEMM_TILE(W1n, XS, EDIM, kb, 32, acc);
    P_STORE(P, kg, jc, acc);
  }
  __syncthreads();
  if (t < 256) { // H reduce
    float4 s; P_REDUCE8(P, t, b1[(size_t)n * EDIM + t], s);
    *(float4*)&H[t * 4] = make_float4(fmaxf(s.x, 0.f), fmaxf(s.y, 0.f),
                                      fmaxf(s.z, 0.f), fmaxf(s.w, 0.f));
  }
  __syncthreads();
  { float acc[4][4] = {};
    GEMM_TILE_H(W2n, H, kb, 32, acc);
    P_STORE(P, kg, jc, acc);
  }
  __syncthreads();
  if (t < 256) { // epilogue: relu/denom -> state (in-place)
    float4 s; P_REDUCE8(P, t, b2[(size_t)n * EDIM + t], s);
    float sv[4] = { s.x, s.y, s.z, s.w };
#pragma unroll
    for (int i = 0; i < 4; i++) {
      if (i < m) {
        const int row = rowsl[i] & 1023;
        state[(size_t)row * EDIM + t] = fmaxf(sv[i], 0.f) / denom[i];
      }
    }
  }
}

// ============ B4 + head (grid 304, 512 thr) ============
__global__ __launch_bounds__(512, 2) void k_block_final(
    const float* __restrict__ state,
    const float* __restrict__ W1, const float* __restrict__ b1,
    const float* __restrict__ W2, const float* __restrict__ b2,
    const float* __restrict__ initial,
    const float* __restrict__ oW1, const float* __restrict__ ob1,
    const float* __restrict__ oW2, const float* __restrict__ ob2,
    const int* __restrict__ nn4, float* __restrict__ out) {
  __shared__ __align__(16) float XS[4 * EDIM];
  __shared__ __align__(16) float P[8 * 256 * 4];
  __shared__ __align__(16) float H[EDIM * 4];
  __shared__ __align__(16) float P2h[32 * 16 * 4];   // 8 KB
  __shared__ int hist[64], meta[4], rowsl[4];
  __shared__ int wcnt2[16], wbase2[16];
  __shared__ float denom[4];
  const int t = threadIdx.x;
  const int c = ((blockIdx.x & 7) * 38) + (blockIdx.x >> 3);
  const int jc = t & 63, kg = t >> 6;

  B_ROUTE(max(nn4[rr], 0))   // exited rows re-enter at origin

  if (t < 256) {
    const int i = t >> 6, q = t & 63;
    const int row = rowsl[min(i, m - 1)] & 1023;
    const float4 v = *(const float4*)(state + (size_t)row * EDIM + q * 4);
    ((float4*)XS)[t] = v;
    float sq = v.x * v.x + v.y * v.y + v.z * v.z + v.w * v.w;
#pragma unroll
    for (int d = 32; d >= 1; d >>= 1) sq += __shfl_xor(sq, d);
    if (q == 0) denom[i] = sqrtf(sq) + 1e-6f;
  }
  __syncthreads();

  const float* W1n = W1 + (size_t)n * EDIM * EDIM;
  const float* W2n = W2 + (size_t)n * EDIM * EDIM;
  const int kb = kg * 32;
  { float acc[4][4] = {};
    GEMM_TILE(W1n, XS, EDIM, kb, 32, acc);
    P_STORE(P, kg, jc, acc);
  }
  __syncthreads();
  if (t < 256) {
    float4 s; P_REDUCE8(P, t, b1[(size_t)n * EDIM + t], s);
    *(float4*)&H[t * 4] = make_float4(fmaxf(s.x, 0.f), fmaxf(s.y, 0.f),
                                      fmaxf(s.z, 0.f), fmaxf(s.w, 0.f));
  }
  __syncthreads();
  { float acc[4][4] = {};
    GEMM_TILE_H(W2n, H, kb, 32, acc);
    P_STORE(P, kg, jc, acc);
  }
  __syncthreads();
  if (t < 256) { // final_output = relu/denom + initial -> XS (head input)
    float4 s; P_REDUCE8(P, t, b2[(size_t)n * EDIM + t], s);
    float sv[4] = { s.x, s.y, s.z, s.w };
#pragma unroll
    for (int i = 0; i < 4; i++) {
      const int row = rowsl[i] & 1023;
      float v = fmaxf(sv[i], 0.f) / denom[i];
      v += initial[(size_t)row * EDIM + t];
      XS[i * EDIM + t] = v;     // dup rows for i>=m harmless (guard at out)
    }
  }
  __syncthreads();

  // ---- head layer 1 (oW1) ----
  { float acc[4][4] = {};
    GEMM_TILE(oW1, XS, EDIM, kb, 32, acc);
    P_STORE(P, kg, jc, acc);
  }
  __syncthreads();
  if (t < 256) {
    float4 s; P_REDUCE8(P, t, ob1[t], s);
    *(float4*)&H[t * 4] = make_float4(fmaxf(s.x, 0.f), fmaxf(s.y, 0.f),
                                      fmaxf(s.z, 0.f), fmaxf(s.w, 0.f));
  }
  __syncthreads();
  { // head layer 2: 32 slices of 8
    const int cc = t & 15, ksl = t >> 4;
    float a2[4] = {0.f, 0.f, 0.f, 0.f};
    if (cc < 10) {
      const int k0 = ksl * 8;
#pragma unroll
      for (int k = k0; k < k0 + 8; k++) {
        const float4 h = *(const float4*)&H[k * 4];
        const float w = oW2[k * 10 + cc];
        a2[0] = fmaf(h.x, w, a2[0]); a2[1] = fmaf(h.y, w, a2[1]);
        a2[2] = fmaf(h.z, w, a2[2]); a2[3] = fmaf(h.w, w, a2[3]);
      }
    }
    *(float4*)&P2h[(ksl * 16 + cc) * 4] = make_float4(a2[0], a2[1], a2[2], a2[3]);
  }
  __syncthreads();
  if (t < 40) {
    const int i = t / 10, cc = t % 10;
    if (i < m) {
      float s = 0.f;
#pragma unroll
      for (int w = 0; w < 32; w++) s += P2h[(w * 16 + cc) * 4 + i];
      const int row = rowsl[i] & 1023;
      out[(size_t)row * 10 + cc] = s + ob2[cc];
    }
  }
}

// ---------------- launch: 10 dispatches ----------------
extern "C" void kernel_launch(void* const* d_in, const int* in_sizes, int n_in,
                              void* d_out, int out_size, void* d_ws, size_t ws_size,
                              hipStream_t stream) {
  const float* x    = (const float*)d_in[0];
  const float* Wemb = (const float*)d_in[1];
  const float* bemb = (const float*)d_in[2];
  const float* stW1 = (const float*)d_in[3];
  const float* stb1 = (const float*)d_in[4];
  const float* stW2 = (const float*)d_in[5];
  const float* stb2 = (const float*)d_in[6];
  const float* aW1  = (const float*)d_in[7];
  const float* ab1  = (const float*)d_in[8];
  const float* aW2  = (const float*)d_in[9];
  const float* ab2  = (const float*)d_in[10];
  const float* oW1  = (const float*)d_in[11];
  const float* ob1  = (const float*)d_in[12];
  const float* oW2  = (const float*)d_in[13];
  const float* ob2  = (const float*)d_in[14];
  float* out = (float*)d_out;

  char* ws = (char*)d_ws;
  auto alloc = [&](size_t bytes) { char* p = ws; ws += (bytes + 255) & ~(size_t)255; return p; };
  float* state   = (float*)alloc((size_t)BATCH * EDIM * 4);
  float* initial = (float*)alloc((size_t)BATCH * EDIM * 4);
  int*   nn_all  = (int*)alloc(5 * BATCH * 4);

  k_embed_a0<<<BATCH / 4, 512, 0, stream>>>(x, Wemb, bemb, aW1, ab1, aW2, ab2,
                                            state, initial, nn_all);
  for (int j = 0; j < 4; j++) {
    k_blocks<<<GRID_B, 512, 0, stream>>>(state, stW1, stb1, stW2, stb2,
                                         nn_all + j * BATCH);
    k_addr<<<BATCH / 4, 512, 0, stream>>>(state, aW1, ab1, aW2, ab2,
                                          nn_all + j * BATCH,
                                          nn_all + (j + 1) * BATCH, j + 1);
  }
  k_block_final<<<GRID_B, 512, 0, stream>>>(state, stW1, stb1, stW2, stb2,
                                            initial, oW1, ob1, oW2, ob2,
                                            nn_all + 4 * BATCH, out);
}